// Round 1
// 493.058 us; speedup vs baseline: 1.0116x; 1.0116x over previous
//
#include <hip/hip_runtime.h>

// RepetHead: 4 layers of (3x3 offset conv -> DCNv1 deform conv -> ReLU)
// B=4, C=256, H=W=64, K=9 taps.
// Round 7: deform block restructured from M=64 x N=128 to M=32 x N=256
// (same 512-block grid, 2 blocks/CU, same per-wave MFMA count). The
// bilinear gather+combine+hi/lo-split of the A tile is now staged ONCE
// per (b,h,w-half) instead of twice (the N-split duplicated it), halving
// the dominant VALU cost. bf16 conversion via native (__bf16) casts
// (v_cvt_pk_bf16_f32) instead of integer RNE emulation; gather address
// multiply hoisted to once per tap; staging writes are bank-uniform.
//
// ws layout (floats):
//   offs :   294,912
//   wph  : 1,179,648  (2,359,296 ushort, deform B frag-packed, bf16-hi)
//   owph :   147,456  (  294,912 ushort, offset-conv B frag-packed)
//   xTA  : 2,097,152  (4,194,304 ushort, plane ping)
//   xTB  : 2,097,152  (4,194,304 ushort, plane pong)
// total 5,816,320 floats = 23.3 MB

#define HW 4096

typedef __attribute__((ext_vector_type(8))) __bf16 bf16x8;
typedef __attribute__((ext_vector_type(4))) float f32x4;
typedef __attribute__((ext_vector_type(8))) unsigned short u16x8;
typedef __attribute__((ext_vector_type(4))) unsigned short u16x4;

__device__ inline unsigned int f2bf_bits(float f) {
  unsigned int u = __float_as_uint(f);
  return (u + 0x7fffu + ((u >> 16) & 1u)) >> 16;   // RNE to bf16
}
__device__ inline unsigned short f2bf_rne(float f) {
  return __builtin_bit_cast(unsigned short, (__bf16)f);
}
__device__ inline float bf_hi_f(unsigned short h) {
  return __uint_as_float(((unsigned int)h) << 16);
}

// ---------------------------------------------------------------------------
// w[r][o][c][ky][kx] -> frag-packed wph[r][q=72][nt=16][lane=64][j=8] (bf16-hi)
// n = nt*16+(lane&15); kk = q*32+(lane>>4)*8+j; c = kk&255; k = kk>>8.
__global__ __launch_bounds__(256) void wpack_kernel(
    const float* __restrict__ w, unsigned short* __restrict__ wph) {
  const int f = blockIdx.x * 256 + threadIdx.x;   // < 2,359,296
  const int j  = f & 7;
  const int l  = (f >> 3) & 63;
  const int nt = (f >> 9) & 15;
  const int q  = (f >> 13) % 72;
  const int r  = f / 589824;
  const int n  = nt * 16 + (l & 15);
  const int kk = q * 32 + ((l >> 4) << 3) + j;
  const int c  = kk & 255, k = kk >> 8;
  wph[f] = (unsigned short)f2bf_bits(w[((r * 256 + n) * 256 + c) * 9 + k]);
}

// offw[r][18][256][3][3] -> owph[r][q=72][nt=2][lane=64][j=8] (n>=18 -> 0)
__global__ __launch_bounds__(256) void offwpack_kernel(
    const float* __restrict__ offw, unsigned short* __restrict__ owph) {
  const int f = blockIdx.x * 256 + threadIdx.x;   // < 294,912
  const int j  = f & 7;
  const int l  = (f >> 3) & 63;
  const int nt = (f >> 9) & 1;
  const int q  = (f >> 10) % 72;
  const int r  = f / 73728;
  const int n  = nt * 16 + (l & 15);
  const int kk = q * 32 + ((l >> 4) << 3) + j;
  const int c  = kk & 255, k = kk >> 8;
  const float v = (n < 18) ? offw[((r * 18 + n) * 256 + c) * 9 + k] : 0.f;
  owph[f] = (unsigned short)f2bf_bits(v);
}

// ---------------------------------------------------------------------------
// x [4][256][4096] fp32 -> xT [4][4096][256] bf16-hi (transpose + cast)
__global__ __launch_bounds__(256) void xpose_kernel(
    const float* __restrict__ x, unsigned short* __restrict__ xh) {
  const int p0 = blockIdx.x * 64;     // pos tile
  const int c0 = blockIdx.y * 64;     // channel tile
  const int b  = blockIdx.z;
  __shared__ float sT[64][65];
  const int t = threadIdx.x;
  const int pj = t & 63, ci0 = (t >> 6) * 16;
  const float* __restrict__ xb = x + ((size_t)(b * 256 + c0)) * HW + p0;
#pragma unroll
  for (int u = 0; u < 16; ++u)
    sT[ci0 + u][pj] = xb[(size_t)(ci0 + u) * HW + pj];
  __syncthreads();
  const int pr = t >> 2, cs = (t & 3) * 16;
  u16x8 va, vb;
#pragma unroll
  for (int u = 0; u < 8; ++u) va[u] = (unsigned short)f2bf_bits(sT[cs + u][pr]);
#pragma unroll
  for (int u = 0; u < 8; ++u) vb[u] = (unsigned short)f2bf_bits(sT[cs + 8 + u][pr]);
  const size_t o = ((size_t)b * HW + p0 + pr) * 256 + c0 + cs;
  *(u16x8*)(xh + o) = va;
  *(u16x8*)(xh + o + 8) = vb;
}

// ---------------------------------------------------------------------------
// Offset conv, zero-LDS MFMA (r4-proven). block = 32m x 32n, 4 waves.
__global__ __launch_bounds__(256) void offconv_mfma(
    const unsigned short* __restrict__ xh,
    const unsigned short* __restrict__ owh,
    const float* __restrict__ bias, float* __restrict__ offs) {
  const int gid = blockIdx.x;                 // 0..511
  const int b = (gid & 7) >> 1;
  const int idx = ((gid >> 3) << 1) | (gid & 1);   // 0..127
  const int h = idx >> 1, w0 = (idx & 1) << 5;
  const int t = threadIdx.x, lane = t & 63, wv = t >> 6;
  const int frow = lane & 15, fgrp = lane >> 4;
  const int mt = wv & 1, nt = wv >> 1;
  const int m = w0 + mt * 16 + frow;          // w coordinate of A row

  f32x4 acc = {0.f, 0.f, 0.f, 0.f};
  const u16x8 z8 = {};
  const size_t xb = (size_t)b * HW;

  for (int k = 0; k < 9; ++k) {
    const int ky = k / 3 - 1, kx = k % 3 - 1;
    if ((unsigned)(h + ky) >= 64u) continue;  // block-uniform: tap row is 0
    const bool vpx = (unsigned)(m + kx) < 64u;
    const int cpx = (m + kx) < 0 ? 0 : ((m + kx) > 63 ? 63 : (m + kx));
    const size_t abase = (xb + (size_t)((h + ky) * 64 + cpx)) * 256 + fgrp * 8;
#pragma unroll
    for (int cc = 0; cc < 8; ++cc) {
      const int q = k * 8 + cc;
      u16x8 ahr = *(const u16x8*)(xh + abase + cc * 32);
      if (!vpx) ahr = z8;
      const u16x8 bhr = ((const u16x8*)owh)[(q * 2 + nt) * 64 + lane];
      const bf16x8 ah = __builtin_bit_cast(bf16x8, ahr);
      const bf16x8 bh = __builtin_bit_cast(bf16x8, bhr);
      acc = __builtin_amdgcn_mfma_f32_16x16x32_bf16(ah, bh, acc, 0, 0, 0);
    }
  }
  const int oc = nt * 16 + frow;              // C/D: col = lane&15 -> n
  if (oc < 18) {
    const float bv = bias[oc];
    const int wbase = w0 + mt * 16 + fgrp * 4;  // C/D: row = (lane>>4)*4 + r
    float* __restrict__ op = offs + (size_t)(b * 18 + oc) * HW + h * 64 + wbase;
#pragma unroll
    for (int r = 0; r < 4; ++r) op[r] = acc[r] + bv;
  }
}

// ---------------------------------------------------------------------------
// Fused bilinear-sample + bf16 MFMA GEMM + ReLU, software-pipelined with
// LITERAL double-buffer indices (no runtime-indexed register arrays).
// Block: M=32 (half row), N=256 (ALL output channels). 4 waves, each wave
// owns a 64-channel slice: 2 m-tiles x 4 n-tiles x 2 (hi/lo) products.
// A tile is gathered+combined exactly once per block (no N-duplication).
__global__ __launch_bounds__(256) void deform_mfma(
    const unsigned short* __restrict__ xh,   // [4][4096][256] bf16-hi plane
    const float* __restrict__ offs,          // [4][18][4096]
    const unsigned short* __restrict__ wph,  // [72][16][64][8] this layer
    unsigned short* __restrict__ yth,        // next plane (layers 0-2)
    float* __restrict__ outf) {              // fp32 NCHW out (layer 3)
  const int gid = blockIdx.x;                  // 0..511
  const int b = (gid & 7) >> 1;                // 2 XCDs per batch image
  const int idx = ((gid >> 3) << 1) | (gid & 1);   // 0..127
  const int h = idx >> 1, w0 = (idx & 1) << 5;     // half-row of 32
  const int t = threadIdx.x, lane = t & 63, nw = t >> 6;
  const int frow = lane & 15, quad = lane >> 4;
  const int sm = t & 31, cg = t >> 5;          // staging: m, 4-channel group

  __shared__ __align__(16) unsigned char smem[19456];
  float* s_cw = (float*)smem;                  // [9][4][32] = 4608 B
  int*   s_ci = (int*)(smem + 4608);           // [9][4][32] = 4608 B
  unsigned short (*sA)[2][32][40] =
      (unsigned short (*)[2][32][40])(smem + 9216);  // 2 bufs = 10240 B

  // phase 0: per (k, m) bilinear setup, m = w coordinate within half-row
  for (int i = t; i < 288; i += 256) {
    const int k = i >> 5, m = i & 31;
    const int ky = k / 3 - 1, kx = k % 3 - 1;
    const int mw = w0 + m;
    const int pos = h * 64 + mw;
    const float dy = offs[(b * 18 + 2 * k) * HW + pos];
    const float dx = offs[(b * 18 + 2 * k + 1) * HW + pos];
    const float py = (float)(h + ky) + dy;
    const float px = (float)(mw + kx) + dx;
    const float y0f = floorf(py), x0f = floorf(px);
    const float wy = py - y0f, wx = px - x0f;
    const int y0 = (int)y0f, x0 = (int)x0f;
#pragma unroll
    for (int j = 0; j < 4; ++j) {
      const int yi = y0 + (j >> 1), xi = x0 + (j & 1);
      const bool v = (yi >= 0) && (yi < 64) && (xi >= 0) && (xi < 64);
      const float wgt = ((j >> 1) ? wy : 1.f - wy) * ((j & 1) ? wx : 1.f - wx);
      s_cw[(k * 4 + j) * 32 + m] = v ? wgt : 0.f;
      const int yc = yi < 0 ? 0 : (yi > 63 ? 63 : yi);
      const int xc = xi < 0 ? 0 : (xi > 63 ? 63 : xi);
      s_ci[(k * 4 + j) * 32 + m] = yc * 64 + xc;
    }
  }
  __syncthreads();

  f32x4 acc[2][4];
#pragma unroll
  for (int mt = 0; mt < 2; ++mt)
#pragma unroll
    for (int nt = 0; nt < 4; ++nt) acc[mt][nt] = (f32x4){0.f, 0.f, 0.f, 0.f};

  const char* __restrict__ xbc = (const char*)(xh + (size_t)b * HW * 256);
  const u16x8* __restrict__ wp = (const u16x8*)wph;
  const int bfo = nw * 4;                      // wave's n-tile base

  u16x4 G0[4], G1[4];
  u16x8 B0[4], B1[4];
  float cwr[4]; int cib[4];
#pragma unroll
  for (int j = 0; j < 4; ++j) {   // tap 0 staging params (byte offsets)
    cwr[j] = s_cw[j * 32 + sm];
    cib[j] = s_ci[j * 32 + sm] * 512;
  }
#pragma unroll
  for (int j = 0; j < 4; ++j)     // chunk 0 gather (byte c0 = cg*8)
    G0[j] = *(const u16x4*)(xbc + cib[j] + cg * 8);
#pragma unroll
  for (int i = 0; i < 4; ++i)     // chunk 0 B frags
    B0[i] = wp[(bfo + i) * 64 + lane];

#define COMBINE_STORE(Gx, buf)                                              \
  {                                                                         \
    u16x4 hv, lv;                                                           \
    _Pragma("unroll") for (int u = 0; u < 4; ++u) {                         \
      float s = cwr[0] * bf_hi_f(Gx[0][u]);                                 \
      s = fmaf(cwr[1], bf_hi_f(Gx[1][u]), s);                               \
      s = fmaf(cwr[2], bf_hi_f(Gx[2][u]), s);                               \
      s = fmaf(cwr[3], bf_hi_f(Gx[3][u]), s);                               \
      const unsigned short hb = f2bf_rne(s);                                \
      hv[u] = hb;                                                           \
      lv[u] = f2bf_rne(s - bf_hi_f(hb));                                    \
    }                                                                       \
    *(u16x4*)&sA[buf][0][sm][cg * 4] = hv;                                  \
    *(u16x4*)&sA[buf][1][sm][cg * 4] = lv;                                  \
  }

#define MFMA_BODY(buf, Bx)                                                  \
  {                                                                         \
    bf16x8 ah[2], al[2];                                                    \
    _Pragma("unroll") for (int mt = 0; mt < 2; ++mt) {                      \
      const int row = mt * 16 + frow;                                       \
      ah[mt] = __builtin_bit_cast(bf16x8,                                   \
                                  *(const u16x8*)&sA[buf][0][row][quad * 8]); \
      al[mt] = __builtin_bit_cast(bf16x8,                                   \
                                  *(const u16x8*)&sA[buf][1][row][quad * 8]); \
    }                                                                       \
    _Pragma("unroll") for (int nt = 0; nt < 4; ++nt) {                      \
      const bf16x8 bv = __builtin_bit_cast(bf16x8, Bx[nt]);                 \
      _Pragma("unroll") for (int mt = 0; mt < 2; ++mt) {                    \
        acc[mt][nt] = __builtin_amdgcn_mfma_f32_16x16x32_bf16(              \
            ah[mt], bv, acc[mt][nt], 0, 0, 0);                              \
        acc[mt][nt] = __builtin_amdgcn_mfma_f32_16x16x32_bf16(              \
            al[mt], bv, acc[mt][nt], 0, 0, 0);                              \
      }                                                                     \
    }                                                                       \
  }

  for (int it = 0; it < 36; ++it) {
    const int cc0 = it * 2;
    // ---- body A: chunk cc0 (regs G0/B0) -> sA[0]; prefetch cc0+1 -> G1/B1
    COMBINE_STORE(G0, 0)
    __syncthreads();
    {
      const int c0b = ((cc0 + 1) & 7) * 64 + cg * 8;   // same tap (cc0+1 odd)
#pragma unroll
      for (int j = 0; j < 4; ++j)
        G1[j] = *(const u16x4*)(xbc + cib[j] + c0b);
#pragma unroll
      for (int i = 0; i < 4; ++i)
        B1[i] = wp[((cc0 + 1) * 16 + bfo + i) * 64 + lane];
    }
    MFMA_BODY(0, B0)
    // ---- body B: chunk cc0+1 (regs G1/B1) -> sA[1]; prefetch cc0+2 -> G0/B0
    COMBINE_STORE(G1, 1)
    __syncthreads();
    if (it < 35) {
      const int cc2 = cc0 + 2;
      if ((cc2 & 7) == 0) {                    // new tap (cc2 even only)
        const int k = cc2 >> 3;
#pragma unroll
        for (int j = 0; j < 4; ++j) {
          cwr[j] = s_cw[(k * 4 + j) * 32 + sm];
          cib[j] = s_ci[(k * 4 + j) * 32 + sm] * 512;
        }
      }
      const int c0b = (cc2 & 7) * 64 + cg * 8;
#pragma unroll
      for (int j = 0; j < 4; ++j)
        G0[j] = *(const u16x4*)(xbc + cib[j] + c0b);
#pragma unroll
      for (int i = 0; i < 4; ++i)
        B0[i] = wp[(cc2 * 16 + bfo + i) * 64 + lane];
    }
    MFMA_BODY(1, B1)
  }
#undef COMBINE_STORE
#undef MFMA_BODY

  if (outf) {
    // final layer: ReLU + direct fp32 NCHW scatter (float4 per tile-row)
#pragma unroll
    for (int mt = 0; mt < 2; ++mt)
#pragma unroll
      for (int nt = 0; nt < 4; ++nt) {
        const int n = nw * 64 + nt * 16 + frow;
        const int pos = h * 64 + w0 + mt * 16 + quad * 4;
        float4 vv;
        vv.x = fmaxf(acc[mt][nt][0], 0.f);
        vv.y = fmaxf(acc[mt][nt][1], 0.f);
        vv.z = fmaxf(acc[mt][nt][2], 0.f);
        vv.w = fmaxf(acc[mt][nt][3], 0.f);
        *(float4*)&outf[(size_t)(b * 256 + n) * HW + pos] = vv;
      }
  } else {
    // layers 0-2: ReLU + bf16-hi transposed plane via per-wave LDS slice
    __syncthreads();   // all K-loop smem/sA traffic done before union reuse
    unsigned short* sW = (unsigned short*)smem + nw * (32 * 72);  // [32][72]
#pragma unroll
    for (int mt = 0; mt < 2; ++mt)
#pragma unroll
      for (int nt = 0; nt < 4; ++nt)
#pragma unroll
        for (int r = 0; r < 4; ++r)
          sW[(mt * 16 + quad * 4 + r) * 72 + nt * 16 + frow] =
              f2bf_rne(fmaxf(acc[mt][nt][r], 0.f));
    __syncthreads();
    const int lm = lane & 31, cg2 = lane >> 5;
    const int pos = h * 64 + w0 + lm;
    unsigned short* __restrict__ yp =
        yth + ((size_t)b * HW + pos) * 256 + nw * 64 + cg2 * 32;
#pragma unroll
    for (int g = 0; g < 4; ++g)
      *(u16x8*)(yp + g * 8) = *(const u16x8*)&sW[lm * 72 + cg2 * 32 + g * 8];
  }
}

extern "C" void kernel_launch(void* const* d_in, const int* in_sizes, int n_in,
                              void* d_out, int out_size, void* d_ws, size_t ws_size,
                              hipStream_t stream) {
  const float* x0   = (const float*)d_in[0];  // [4][256][64][64]
  const float* offw = (const float*)d_in[1];  // [4][18][256][3][3]
  const float* offb = (const float*)d_in[2];  // [4][18]
  const float* w    = (const float*)d_in[3];  // [4][256][256][3][3]
  float* out = (float*)d_out;                 // [4][256][64][64]
  float* ws  = (float*)d_ws;

  float* offs = ws;                                     //   294,912 floats
  unsigned short* wph  = (unsigned short*)(ws + 294912);    // 2,359,296 ushort
  unsigned short* owph = wph + 2359296;                     //   294,912 ushort
  unsigned short* xTA  = owph + 294912;                     // 4,194,304 ushort
  unsigned short* xTB  = xTA + 4194304;                     // 4,194,304 ushort

  wpack_kernel<<<9216, 256, 0, stream>>>(w, wph);
  offwpack_kernel<<<1152, 256, 0, stream>>>(offw, owph);
  xpose_kernel<<<dim3(64, 4, 4), 256, 0, stream>>>(x0, xTA);

  unsigned short* pin = xTA;
  unsigned short* pout = xTB;
  for (int r = 0; r < 4; ++r) {
    offconv_mfma<<<512, 256, 0, stream>>>(pin, owph + r * 73728,
                                          offb + r * 18, offs);
    deform_mfma<<<512, 256, 0, stream>>>(pin, offs,
                                         wph + (size_t)r * 589824,
                                         (r < 3) ? pout : nullptr,
                                         (r < 3) ? nullptr : out);
    unsigned short* tmp = pin; pin = pout; pout = tmp;
  }
}

// Round 2
// 372.351 us; speedup vs baseline: 1.3395x; 1.3242x over previous
//
#include <hip/hip_runtime.h>

// RepetHead: 4 layers of (3x3 offset conv -> DCNv1 deform conv -> ReLU)
// B=4, C=256, H=W=64, K=9 taps.
// Round 8: deform kernel goes 256 -> 512 threads (8 waves/block) at the
// same M=32 x N=256 geometry and 512-block grid: 4 waves/SIMD instead of
// 2, attacking the 64% stall fraction (latency/barrier-bound; VALU 20%,
// MFMA 17%, L2 traffic ~20% of peak). Per wave: 2 m-tiles x 2 n-tiles.
// Staging remap (row = t>>4, cg = t&15): 64B-contiguous gather runs and
// ~2-way (vs 4-way) LDS write banking; A-frag layout/order unchanged.
//
// ws layout (floats):
//   offs :   294,912
//   wph  : 1,179,648  (2,359,296 ushort, deform B frag-packed, bf16-hi)
//   owph :   147,456  (  294,912 ushort, offset-conv B frag-packed)
//   xTA  : 2,097,152  (4,194,304 ushort, plane ping)
//   xTB  : 2,097,152  (4,194,304 ushort, plane pong)
// total 5,816,320 floats = 23.3 MB

#define HW 4096

typedef __attribute__((ext_vector_type(8))) __bf16 bf16x8;
typedef __attribute__((ext_vector_type(4))) float f32x4;
typedef __attribute__((ext_vector_type(8))) unsigned short u16x8;

__device__ inline unsigned int f2bf_bits(float f) {
  unsigned int u = __float_as_uint(f);
  return (u + 0x7fffu + ((u >> 16) & 1u)) >> 16;   // RNE to bf16
}
__device__ inline float bf_hi_f(unsigned short h) {
  return __uint_as_float(((unsigned int)h) << 16);
}

// ---------------------------------------------------------------------------
// w[r][o][c][ky][kx] -> frag-packed wph[r][q=72][nt=16][lane=64][j=8] (bf16-hi)
// n = nt*16+(lane&15); kk = q*32+(lane>>4)*8+j; c = kk&255; k = kk>>8.
__global__ __launch_bounds__(256) void wpack_kernel(
    const float* __restrict__ w, unsigned short* __restrict__ wph) {
  const int f = blockIdx.x * 256 + threadIdx.x;   // < 2,359,296
  const int j  = f & 7;
  const int l  = (f >> 3) & 63;
  const int nt = (f >> 9) & 15;
  const int q  = (f >> 13) % 72;
  const int r  = f / 589824;
  const int n  = nt * 16 + (l & 15);
  const int kk = q * 32 + ((l >> 4) << 3) + j;
  const int c  = kk & 255, k = kk >> 8;
  wph[f] = (unsigned short)f2bf_bits(w[((r * 256 + n) * 256 + c) * 9 + k]);
}

// offw[r][18][256][3][3] -> owph[r][q=72][nt=2][lane=64][j=8] (n>=18 -> 0)
__global__ __launch_bounds__(256) void offwpack_kernel(
    const float* __restrict__ offw, unsigned short* __restrict__ owph) {
  const int f = blockIdx.x * 256 + threadIdx.x;   // < 294,912
  const int j  = f & 7;
  const int l  = (f >> 3) & 63;
  const int nt = (f >> 9) & 1;
  const int q  = (f >> 10) % 72;
  const int r  = f / 73728;
  const int n  = nt * 16 + (l & 15);
  const int kk = q * 32 + ((l >> 4) << 3) + j;
  const int c  = kk & 255, k = kk >> 8;
  const float v = (n < 18) ? offw[((r * 18 + n) * 256 + c) * 9 + k] : 0.f;
  owph[f] = (unsigned short)f2bf_bits(v);
}

// ---------------------------------------------------------------------------
// x [4][256][4096] fp32 -> xT [4][4096][256] bf16-hi (transpose + cast)
__global__ __launch_bounds__(256) void xpose_kernel(
    const float* __restrict__ x, unsigned short* __restrict__ xh) {
  const int p0 = blockIdx.x * 64;     // pos tile
  const int c0 = blockIdx.y * 64;     // channel tile
  const int b  = blockIdx.z;
  __shared__ float sT[64][65];
  const int t = threadIdx.x;
  const int pj = t & 63, ci0 = (t >> 6) * 16;
  const float* __restrict__ xb = x + ((size_t)(b * 256 + c0)) * HW + p0;
#pragma unroll
  for (int u = 0; u < 16; ++u)
    sT[ci0 + u][pj] = xb[(size_t)(ci0 + u) * HW + pj];
  __syncthreads();
  const int pr = t >> 2, cs = (t & 3) * 16;
  u16x8 va, vb;
#pragma unroll
  for (int u = 0; u < 8; ++u) va[u] = (unsigned short)f2bf_bits(sT[cs + u][pr]);
#pragma unroll
  for (int u = 0; u < 8; ++u) vb[u] = (unsigned short)f2bf_bits(sT[cs + 8 + u][pr]);
  const size_t o = ((size_t)b * HW + p0 + pr) * 256 + c0 + cs;
  *(u16x8*)(xh + o) = va;
  *(u16x8*)(xh + o + 8) = vb;
}

// ---------------------------------------------------------------------------
// Offset conv, zero-LDS MFMA (r4-proven). block = 32m x 32n, 4 waves.
__global__ __launch_bounds__(256) void offconv_mfma(
    const unsigned short* __restrict__ xh,
    const unsigned short* __restrict__ owh,
    const float* __restrict__ bias, float* __restrict__ offs) {
  const int gid = blockIdx.x;                 // 0..511
  const int b = (gid & 7) >> 1;
  const int idx = ((gid >> 3) << 1) | (gid & 1);   // 0..127
  const int h = idx >> 1, w0 = (idx & 1) << 5;
  const int t = threadIdx.x, lane = t & 63, wv = t >> 6;
  const int frow = lane & 15, fgrp = lane >> 4;
  const int mt = wv & 1, nt = wv >> 1;
  const int m = w0 + mt * 16 + frow;          // w coordinate of A row

  f32x4 acc = {0.f, 0.f, 0.f, 0.f};
  const u16x8 z8 = {};
  const size_t xb = (size_t)b * HW;

  for (int k = 0; k < 9; ++k) {
    const int ky = k / 3 - 1, kx = k % 3 - 1;
    if ((unsigned)(h + ky) >= 64u) continue;  // block-uniform: tap row is 0
    const bool vpx = (unsigned)(m + kx) < 64u;
    const int cpx = (m + kx) < 0 ? 0 : ((m + kx) > 63 ? 63 : (m + kx));
    const size_t abase = (xb + (size_t)((h + ky) * 64 + cpx)) * 256 + fgrp * 8;
#pragma unroll
    for (int cc = 0; cc < 8; ++cc) {
      const int q = k * 8 + cc;
      u16x8 ahr = *(const u16x8*)(xh + abase + cc * 32);
      if (!vpx) ahr = z8;
      const u16x8 bhr = ((const u16x8*)owh)[(q * 2 + nt) * 64 + lane];
      const bf16x8 ah = __builtin_bit_cast(bf16x8, ahr);
      const bf16x8 bh = __builtin_bit_cast(bf16x8, bhr);
      acc = __builtin_amdgcn_mfma_f32_16x16x32_bf16(ah, bh, acc, 0, 0, 0);
    }
  }
  const int oc = nt * 16 + frow;              // C/D: col = lane&15 -> n
  if (oc < 18) {
    const float bv = bias[oc];
    const int wbase = w0 + mt * 16 + fgrp * 4;  // C/D: row = (lane>>4)*4 + r
    float* __restrict__ op = offs + (size_t)(b * 18 + oc) * HW + h * 64 + wbase;
#pragma unroll
    for (int r = 0; r < 4; ++r) op[r] = acc[r] + bv;
  }
}

// ---------------------------------------------------------------------------
// Fused bilinear-sample + bf16 MFMA GEMM + ReLU, software-pipelined with
// LITERAL double-buffer indices. Block: M=32 (half row), N=256 (all output
// channels), 512 threads = 8 waves. Each wave: 2 m-tiles x 2 n-tiles x 2
// (hi/lo) products = 8 MFMAs/chunk. A tile gathered+combined once/block.
__global__ __launch_bounds__(512, 4) void deform_mfma(
    const unsigned short* __restrict__ xh,   // [4][4096][256] bf16-hi plane
    const float* __restrict__ offs,          // [4][18][4096]
    const unsigned short* __restrict__ wph,  // [72][16][64][8] this layer
    unsigned short* __restrict__ yth,        // next plane (layers 0-2)
    float* __restrict__ outf) {              // fp32 NCHW out (layer 3)
  const int gid = blockIdx.x;                  // 0..511
  const int b = (gid & 7) >> 1;                // 2 XCDs per batch image
  const int idx = ((gid >> 3) << 1) | (gid & 1);   // 0..127
  const int h = idx >> 1, w0 = (idx & 1) << 5;     // half-row of 32
  const int t = threadIdx.x, lane = t & 63, wv = t >> 6;   // 8 waves
  const int frow = lane & 15, quad = lane >> 4;
  const int sm = t >> 4, cg = t & 15;          // staging: row 0..31, pair 0..15

  __shared__ __align__(16) unsigned char smem[19456];
  float* s_cw = (float*)smem;                  // [9][4][32] = 4608 B
  int*   s_ci = (int*)(smem + 4608);           // [9][4][32] = 4608 B
  unsigned char* sAb = smem + 9216;            // [2][2][32][40] ushort, 10240 B

  // phase 0: per (k, m) bilinear setup, m = w coordinate within half-row
  for (int i = t; i < 288; i += 512) {
    const int k = i >> 5, m = i & 31;
    const int ky = k / 3 - 1, kx = k % 3 - 1;
    const int mw = w0 + m;
    const int pos = h * 64 + mw;
    const float dy = offs[(b * 18 + 2 * k) * HW + pos];
    const float dx = offs[(b * 18 + 2 * k + 1) * HW + pos];
    const float py = (float)(h + ky) + dy;
    const float px = (float)(mw + kx) + dx;
    const float y0f = floorf(py), x0f = floorf(px);
    const float wy = py - y0f, wx = px - x0f;
    const int y0 = (int)y0f, x0 = (int)x0f;
#pragma unroll
    for (int j = 0; j < 4; ++j) {
      const int yi = y0 + (j >> 1), xi = x0 + (j & 1);
      const bool v = (yi >= 0) && (yi < 64) && (xi >= 0) && (xi < 64);
      const float wgt = ((j >> 1) ? wy : 1.f - wy) * ((j & 1) ? wx : 1.f - wx);
      s_cw[(k * 4 + j) * 32 + m] = v ? wgt : 0.f;
      const int yc = yi < 0 ? 0 : (yi > 63 ? 63 : yi);
      const int xc = xi < 0 ? 0 : (xi > 63 ? 63 : xi);
      s_ci[(k * 4 + j) * 32 + m] = yc * 64 + xc;
    }
  }
  __syncthreads();

  f32x4 acc[2][2];
#pragma unroll
  for (int mt = 0; mt < 2; ++mt)
#pragma unroll
    for (int nt = 0; nt < 2; ++nt) acc[mt][nt] = (f32x4){0.f, 0.f, 0.f, 0.f};

  const char* __restrict__ xbc = (const char*)(xh + (size_t)b * HW * 256);
  const u16x8* __restrict__ wp = (const u16x8*)wph;
  const int bfo = wv * 2;                      // wave's n-tile base (0..14)
  const int wbyte = sm * 80 + cg * 4;          // staging LDS write offset

  unsigned int G0[4], G1[4];
  u16x8 B0[2], B1[2];
  float cwr[4]; int cib[4];
#pragma unroll
  for (int j = 0; j < 4; ++j) {   // tap 0 staging params (byte offsets)
    cwr[j] = s_cw[j * 32 + sm];
    cib[j] = s_ci[j * 32 + sm] * 512;
  }
#pragma unroll
  for (int j = 0; j < 4; ++j)     // chunk 0 gather (byte off = cg*4)
    G0[j] = *(const unsigned int*)(xbc + cib[j] + cg * 4);
#pragma unroll
  for (int i = 0; i < 2; ++i)     // chunk 0 B frags
    B0[i] = wp[(bfo + i) * 64 + lane];

#define COMBINE_STORE(Gx, buf)                                              \
  {                                                                         \
    float s0 = cwr[0] * __uint_as_float(Gx[0] << 16);                       \
    float s1 = cwr[0] * __uint_as_float(Gx[0] & 0xffff0000u);               \
    s0 = fmaf(cwr[1], __uint_as_float(Gx[1] << 16), s0);                    \
    s1 = fmaf(cwr[1], __uint_as_float(Gx[1] & 0xffff0000u), s1);            \
    s0 = fmaf(cwr[2], __uint_as_float(Gx[2] << 16), s0);                    \
    s1 = fmaf(cwr[2], __uint_as_float(Gx[2] & 0xffff0000u), s1);            \
    s0 = fmaf(cwr[3], __uint_as_float(Gx[3] << 16), s0);                    \
    s1 = fmaf(cwr[3], __uint_as_float(Gx[3] & 0xffff0000u), s1);            \
    const unsigned int h0 = f2bf_bits(s0), h1 = f2bf_bits(s1);              \
    const unsigned int l0 = f2bf_bits(s0 - __uint_as_float(h0 << 16));      \
    const unsigned int l1 = f2bf_bits(s1 - __uint_as_float(h1 << 16));      \
    *(unsigned int*)(sAb + (buf) * 5120 + wbyte) = h0 | (h1 << 16);         \
    *(unsigned int*)(sAb + (buf) * 5120 + 2560 + wbyte) = l0 | (l1 << 16);  \
  }

#define MFMA_BODY(buf, Bx)                                                  \
  {                                                                         \
    bf16x8 ah[2], al[2];                                                    \
    _Pragma("unroll") for (int mt = 0; mt < 2; ++mt) {                      \
      const int rb = (mt * 16 + frow) * 80 + quad * 16;                     \
      ah[mt] = __builtin_bit_cast(                                          \
          bf16x8, *(const u16x8*)(sAb + (buf) * 5120 + rb));                \
      al[mt] = __builtin_bit_cast(                                          \
          bf16x8, *(const u16x8*)(sAb + (buf) * 5120 + 2560 + rb));         \
    }                                                                       \
    _Pragma("unroll") for (int nt = 0; nt < 2; ++nt) {                      \
      const bf16x8 bv = __builtin_bit_cast(bf16x8, Bx[nt]);                 \
      _Pragma("unroll") for (int mt = 0; mt < 2; ++mt) {                    \
        acc[mt][nt] = __builtin_amdgcn_mfma_f32_16x16x32_bf16(              \
            ah[mt], bv, acc[mt][nt], 0, 0, 0);                              \
        acc[mt][nt] = __builtin_amdgcn_mfma_f32_16x16x32_bf16(              \
            al[mt], bv, acc[mt][nt], 0, 0, 0);                              \
      }                                                                     \
    }                                                                       \
  }

  for (int it = 0; it < 36; ++it) {
    const int cc0 = it * 2;
    // ---- body A: chunk cc0 (regs G0/B0) -> sA[0]; prefetch cc0+1 -> G1/B1
    COMBINE_STORE(G0, 0)
    __syncthreads();
    {
      const int c0b = ((cc0 + 1) & 7) * 64 + cg * 4;   // same tap (cc0+1 odd)
#pragma unroll
      for (int j = 0; j < 4; ++j)
        G1[j] = *(const unsigned int*)(xbc + cib[j] + c0b);
#pragma unroll
      for (int i = 0; i < 2; ++i)
        B1[i] = wp[((cc0 + 1) * 16 + bfo + i) * 64 + lane];
    }
    MFMA_BODY(0, B0)
    // ---- body B: chunk cc0+1 (regs G1/B1) -> sA[1]; prefetch cc0+2 -> G0/B0
    COMBINE_STORE(G1, 1)
    __syncthreads();
    if (it < 35) {
      const int cc2 = cc0 + 2;
      if ((cc2 & 7) == 0) {                    // new tap (cc2 even only)
        const int k = cc2 >> 3;
#pragma unroll
        for (int j = 0; j < 4; ++j) {
          cwr[j] = s_cw[(k * 4 + j) * 32 + sm];
          cib[j] = s_ci[(k * 4 + j) * 32 + sm] * 512;
        }
      }
      const int c0b = (cc2 & 7) * 64 + cg * 4;
#pragma unroll
      for (int j = 0; j < 4; ++j)
        G0[j] = *(const unsigned int*)(xbc + cib[j] + c0b);
#pragma unroll
      for (int i = 0; i < 2; ++i)
        B0[i] = wp[(cc2 * 16 + bfo + i) * 64 + lane];
    }
    MFMA_BODY(1, B1)
  }
#undef COMBINE_STORE
#undef MFMA_BODY

  if (outf) {
    // final layer: ReLU + direct fp32 NCHW scatter (float4 per tile-row)
#pragma unroll
    for (int mt = 0; mt < 2; ++mt)
#pragma unroll
      for (int nt = 0; nt < 2; ++nt) {
        const int n = wv * 32 + nt * 16 + frow;
        const int pos = h * 64 + w0 + mt * 16 + quad * 4;
        float4 vv;
        vv.x = fmaxf(acc[mt][nt][0], 0.f);
        vv.y = fmaxf(acc[mt][nt][1], 0.f);
        vv.z = fmaxf(acc[mt][nt][2], 0.f);
        vv.w = fmaxf(acc[mt][nt][3], 0.f);
        *(float4*)&outf[(size_t)(b * 256 + n) * HW + pos] = vv;
      }
  } else {
    // layers 0-2: ReLU + bf16-hi transposed plane via per-wave LDS slice
    __syncthreads();   // all K-loop smem/sA traffic done before union reuse
    unsigned short* sW = (unsigned short*)smem + wv * (32 * 36);  // [32][36]
#pragma unroll
    for (int mt = 0; mt < 2; ++mt)
#pragma unroll
      for (int nt = 0; nt < 2; ++nt)
#pragma unroll
        for (int r = 0; r < 4; ++r)
          sW[(mt * 16 + quad * 4 + r) * 36 + nt * 16 + frow] =
              (unsigned short)f2bf_bits(fmaxf(acc[mt][nt][r], 0.f));
    __syncthreads();
    const int lm = lane & 31, cg2 = lane >> 5;
    const int pos = h * 64 + w0 + lm;
    unsigned short* __restrict__ yp =
        yth + ((size_t)b * HW + pos) * 256 + wv * 32 + cg2 * 16;
#pragma unroll
    for (int g = 0; g < 2; ++g)
      *(u16x8*)(yp + g * 8) = *(const u16x8*)&sW[lm * 36 + cg2 * 16 + g * 8];
  }
}

extern "C" void kernel_launch(void* const* d_in, const int* in_sizes, int n_in,
                              void* d_out, int out_size, void* d_ws, size_t ws_size,
                              hipStream_t stream) {
  const float* x0   = (const float*)d_in[0];  // [4][256][64][64]
  const float* offw = (const float*)d_in[1];  // [4][18][256][3][3]
  const float* offb = (const float*)d_in[2];  // [4][18]
  const float* w    = (const float*)d_in[3];  // [4][256][256][3][3]
  float* out = (float*)d_out;                 // [4][256][64][64]
  float* ws  = (float*)d_ws;

  float* offs = ws;                                     //   294,912 floats
  unsigned short* wph  = (unsigned short*)(ws + 294912);    // 2,359,296 ushort
  unsigned short* owph = wph + 2359296;                     //   294,912 ushort
  unsigned short* xTA  = owph + 294912;                     // 4,194,304 ushort
  unsigned short* xTB  = xTA + 4194304;                     // 4,194,304 ushort

  wpack_kernel<<<9216, 256, 0, stream>>>(w, wph);
  offwpack_kernel<<<1152, 256, 0, stream>>>(offw, owph);
  xpose_kernel<<<dim3(64, 4, 4), 256, 0, stream>>>(x0, xTA);

  unsigned short* pin = xTA;
  unsigned short* pout = xTB;
  for (int r = 0; r < 4; ++r) {
    offconv_mfma<<<512, 256, 0, stream>>>(pin, owph + r * 73728,
                                          offb + r * 18, offs);
    deform_mfma<<<512, 512, 0, stream>>>(pin, offs,
                                         wph + (size_t)r * 589824,
                                         (r < 3) ? pout : nullptr,
                                         (r < 3) ? nullptr : out);
    unsigned short* tmp = pin; pin = pout; pout = tmp;
  }
}

// Round 3
// 363.551 us; speedup vs baseline: 1.3719x; 1.0242x over previous
//
#include <hip/hip_runtime.h>

// RepetHead: 4 layers of (3x3 offset conv -> DCNv1 deform conv -> ReLU)
// B=4, C=256, H=W=64, K=9 taps.
// Round 9: (a) deform staging LDS gets an XOR swizzle (128B rows, hi slots
// 0-3 / lo slots 4-7, slot ^= g(row), g = ((row&3)<<1)|((row>>2)&1)) making
// both the b32 writes and b128 frag reads 2-way (= free) instead of ~3-way;
// (b) gather/B prefetch distance extended to 2 chunks (issued right after
// the barrier / after the consuming MFMA cluster, consumed a full body
// later ~400+ cyc) to cover L2 latency; tap-boundary params handled by a
// literal 4-unrolled inner loop (boundary is always j4==3).
// (c) offconv goes 256->512 threads: K split across wave halves (cc 0-3 /
// 4-7) + LDS f32x4 reduction -> 4 waves/SIMD.
//
// ws layout (floats):
//   offs :   294,912
//   wph  : 1,179,648  (2,359,296 ushort, deform B frag-packed, bf16-hi)
//   owph :   147,456  (  294,912 ushort, offset-conv B frag-packed)
//   xTA  : 2,097,152  (4,194,304 ushort, plane ping)
//   xTB  : 2,097,152  (4,194,304 ushort, plane pong)
// total 5,816,320 floats = 23.3 MB

#define HW 4096

typedef __attribute__((ext_vector_type(8))) __bf16 bf16x8;
typedef __attribute__((ext_vector_type(4))) float f32x4;
typedef __attribute__((ext_vector_type(8))) unsigned short u16x8;

__device__ inline unsigned int f2bf_bits(float f) {
  unsigned int u = __float_as_uint(f);
  return (u + 0x7fffu + ((u >> 16) & 1u)) >> 16;   // RNE to bf16
}
__device__ inline float bf_hi_f(unsigned short h) {
  return __uint_as_float(((unsigned int)h) << 16);
}

// ---------------------------------------------------------------------------
// w[r][o][c][ky][kx] -> frag-packed wph[r][q=72][nt=16][lane=64][j=8] (bf16-hi)
// n = nt*16+(lane&15); kk = q*32+(lane>>4)*8+j; c = kk&255; k = kk>>8.
__global__ __launch_bounds__(256) void wpack_kernel(
    const float* __restrict__ w, unsigned short* __restrict__ wph) {
  const int f = blockIdx.x * 256 + threadIdx.x;   // < 2,359,296
  const int j  = f & 7;
  const int l  = (f >> 3) & 63;
  const int nt = (f >> 9) & 15;
  const int q  = (f >> 13) % 72;
  const int r  = f / 589824;
  const int n  = nt * 16 + (l & 15);
  const int kk = q * 32 + ((l >> 4) << 3) + j;
  const int c  = kk & 255, k = kk >> 8;
  wph[f] = (unsigned short)f2bf_bits(w[((r * 256 + n) * 256 + c) * 9 + k]);
}

// offw[r][18][256][3][3] -> owph[r][q=72][nt=2][lane=64][j=8] (n>=18 -> 0)
__global__ __launch_bounds__(256) void offwpack_kernel(
    const float* __restrict__ offw, unsigned short* __restrict__ owph) {
  const int f = blockIdx.x * 256 + threadIdx.x;   // < 294,912
  const int j  = f & 7;
  const int l  = (f >> 3) & 63;
  const int nt = (f >> 9) & 1;
  const int q  = (f >> 10) % 72;
  const int r  = f / 73728;
  const int n  = nt * 16 + (l & 15);
  const int kk = q * 32 + ((l >> 4) << 3) + j;
  const int c  = kk & 255, k = kk >> 8;
  const float v = (n < 18) ? offw[((r * 18 + n) * 256 + c) * 9 + k] : 0.f;
  owph[f] = (unsigned short)f2bf_bits(v);
}

// ---------------------------------------------------------------------------
// x [4][256][4096] fp32 -> xT [4][4096][256] bf16-hi (transpose + cast)
__global__ __launch_bounds__(256) void xpose_kernel(
    const float* __restrict__ x, unsigned short* __restrict__ xh) {
  const int p0 = blockIdx.x * 64;     // pos tile
  const int c0 = blockIdx.y * 64;     // channel tile
  const int b  = blockIdx.z;
  __shared__ float sT[64][65];
  const int t = threadIdx.x;
  const int pj = t & 63, ci0 = (t >> 6) * 16;
  const float* __restrict__ xb = x + ((size_t)(b * 256 + c0)) * HW + p0;
#pragma unroll
  for (int u = 0; u < 16; ++u)
    sT[ci0 + u][pj] = xb[(size_t)(ci0 + u) * HW + pj];
  __syncthreads();
  const int pr = t >> 2, cs = (t & 3) * 16;
  u16x8 va, vb;
#pragma unroll
  for (int u = 0; u < 8; ++u) va[u] = (unsigned short)f2bf_bits(sT[cs + u][pr]);
#pragma unroll
  for (int u = 0; u < 8; ++u) vb[u] = (unsigned short)f2bf_bits(sT[cs + 8 + u][pr]);
  const size_t o = ((size_t)b * HW + p0 + pr) * 256 + c0 + cs;
  *(u16x8*)(xh + o) = va;
  *(u16x8*)(xh + o + 8) = vb;
}

// ---------------------------------------------------------------------------
// Offset conv, zero-LDS MFMA main loop. 512 threads = 8 waves:
// (mt, nt, kv) = (wv&1, (wv>>1)&1, wv>>2); K split across kv halves
// (cc = kv*4 + j), combined via an LDS f32x4 reduction at the end.
__global__ __launch_bounds__(512) void offconv_mfma(
    const unsigned short* __restrict__ xh,
    const unsigned short* __restrict__ owh,
    const float* __restrict__ bias, float* __restrict__ offs) {
  const int gid = blockIdx.x;                 // 0..511
  const int b = (gid & 7) >> 1;
  const int idx = ((gid >> 3) << 1) | (gid & 1);   // 0..127
  const int h = idx >> 1, w0 = (idx & 1) << 5;
  const int t = threadIdx.x, lane = t & 63, wv = t >> 6;
  const int frow = lane & 15, fgrp = lane >> 4;
  const int mt = wv & 1, nt = (wv >> 1) & 1, kv = wv >> 2;
  const int m = w0 + mt * 16 + frow;          // w coordinate of A row

  f32x4 acc = {0.f, 0.f, 0.f, 0.f};
  const u16x8 z8 = {};
  const size_t xb = (size_t)b * HW;

  for (int k = 0; k < 9; ++k) {
    const int ky = k / 3 - 1, kx = k % 3 - 1;
    if ((unsigned)(h + ky) < 64u) {           // block-uniform branch
      const bool vpx = (unsigned)(m + kx) < 64u;
      const int cpx = (m + kx) < 0 ? 0 : ((m + kx) > 63 ? 63 : (m + kx));
      const size_t abase = (xb + (size_t)((h + ky) * 64 + cpx)) * 256 + fgrp * 8;
#pragma unroll
      for (int j = 0; j < 4; ++j) {
        const int cc = kv * 4 + j;
        const int q = k * 8 + cc;
        u16x8 ahr = *(const u16x8*)(xh + abase + cc * 32);
        if (!vpx) ahr = z8;
        const u16x8 bhr = ((const u16x8*)owh)[(q * 2 + nt) * 64 + lane];
        const bf16x8 ah = __builtin_bit_cast(bf16x8, ahr);
        const bf16x8 bh = __builtin_bit_cast(bf16x8, bhr);
        acc = __builtin_amdgcn_mfma_f32_16x16x32_bf16(ah, bh, acc, 0, 0, 0);
      }
    }
  }

  __shared__ f32x4 red[2][2][64];             // [mt][nt][lane]
  if (kv == 1) red[mt][nt][lane] = acc;
  __syncthreads();
  if (kv == 0) {
    const f32x4 o = red[mt][nt][lane];
    acc[0] += o[0]; acc[1] += o[1]; acc[2] += o[2]; acc[3] += o[3];
    const int oc = nt * 16 + frow;            // C/D: col = lane&15 -> n
    if (oc < 18) {
      const float bv = bias[oc];
      const int wbase = w0 + mt * 16 + fgrp * 4;  // C/D row = (lane>>4)*4 + r
      float* __restrict__ op =
          offs + (size_t)(b * 18 + oc) * HW + h * 64 + wbase;
#pragma unroll
      for (int r = 0; r < 4; ++r) op[r] = acc[r] + bv;
    }
  }
}

// ---------------------------------------------------------------------------
// Fused bilinear-sample + bf16 MFMA GEMM + ReLU. Block: M=32 (half row),
// N=256, 512 threads = 8 waves (each wave 2 m-tiles x 2 n-tiles x hi/lo).
// Staging LDS: [buf][32 rows][128 B] where row = {hi slots 0-3, lo slots
// 4-7}, slot ^= g(row) -> conflict-free writes AND reads. Gather and B
// prefetch run 2 chunks ahead (full-body distance) to cover L2 latency.
__global__ __launch_bounds__(512, 4) void deform_mfma(
    const unsigned short* __restrict__ xh,   // [4][4096][256] bf16-hi plane
    const float* __restrict__ offs,          // [4][18][4096]
    const unsigned short* __restrict__ wph,  // [72][16][64][8] this layer
    unsigned short* __restrict__ yth,        // next plane (layers 0-2)
    float* __restrict__ outf) {              // fp32 NCHW out (layer 3)
  const int gid = blockIdx.x;                  // 0..511
  const int b = (gid & 7) >> 1;                // 2 XCDs per batch image
  const int idx = ((gid >> 3) << 1) | (gid & 1);   // 0..127
  const int h = idx >> 1, w0 = (idx & 1) << 5;     // half-row of 32
  const int t = threadIdx.x, lane = t & 63, wv = t >> 6;   // 8 waves
  const int frow = lane & 15, quad = lane >> 4;
  const int sm = t >> 4, cg = t & 15;          // staging: row 0..31, pair 0..15

  __shared__ __align__(16) unsigned char smem[18432];
  float* s_cw = (float*)smem;                  // [9][4][32] = 4608 B
  int*   s_ci = (int*)(smem + 4608);           // [9][4][32] = 4608 B
  unsigned char* sAb = smem + 9216;            // [2][32][128 B] = 8192 B

  // phase 0: per (k, m) bilinear setup, m = w coordinate within half-row
  for (int i = t; i < 288; i += 512) {
    const int k = i >> 5, m = i & 31;
    const int ky = k / 3 - 1, kx = k % 3 - 1;
    const int mw = w0 + m;
    const int pos = h * 64 + mw;
    const float dy = offs[(b * 18 + 2 * k) * HW + pos];
    const float dx = offs[(b * 18 + 2 * k + 1) * HW + pos];
    const float py = (float)(h + ky) + dy;
    const float px = (float)(mw + kx) + dx;
    const float y0f = floorf(py), x0f = floorf(px);
    const float wy = py - y0f, wx = px - x0f;
    const int y0 = (int)y0f, x0 = (int)x0f;
#pragma unroll
    for (int j = 0; j < 4; ++j) {
      const int yi = y0 + (j >> 1), xi = x0 + (j & 1);
      const bool v = (yi >= 0) && (yi < 64) && (xi >= 0) && (xi < 64);
      const float wgt = ((j >> 1) ? wy : 1.f - wy) * ((j & 1) ? wx : 1.f - wx);
      s_cw[(k * 4 + j) * 32 + m] = v ? wgt : 0.f;
      const int yc = yi < 0 ? 0 : (yi > 63 ? 63 : yi);
      const int xc = xi < 0 ? 0 : (xi > 63 ? 63 : xi);
      s_ci[(k * 4 + j) * 32 + m] = yc * 64 + xc;
    }
  }
  __syncthreads();

  f32x4 acc[2][2];
#pragma unroll
  for (int mt = 0; mt < 2; ++mt)
#pragma unroll
    for (int nt = 0; nt < 2; ++nt) acc[mt][nt] = (f32x4){0.f, 0.f, 0.f, 0.f};

  const char* __restrict__ xbc = (const char*)(xh + (size_t)b * HW * 256);
  const u16x8* __restrict__ wp = (const u16x8*)wph;
  const int bfo = wv * 2;                      // wave's n-tile base (0..14)

  // XOR-swizzled staging addresses (loop-invariant).
  const int gs = ((sm & 3) << 1) | ((sm >> 2) & 1);
  const int wbA = sm * 128 + ((((cg >> 2) ^ gs)) << 4) + (cg & 3) * 4;  // hi
  const int wbL = wbA ^ 64;                                            // lo
  const int gr = ((frow & 3) << 1) | ((frow >> 2) & 1);
  const int rb0 = frow * 128 + ((quad ^ gr) << 4);        // mt=0 hi
  const int rb1 = rb0 + 2048;                             // mt=1 hi

  unsigned int G0[4], G1[4];
  u16x8 B0[2], B1[2];
  float cwrC[4], cwrN[4];
  int cibC[4], cibN[4];
#pragma unroll
  for (int j = 0; j < 4; ++j) {   // tap 0 staging params (byte offsets)
    cwrC[j] = s_cw[j * 32 + sm];
    cibC[j] = s_ci[j * 32 + sm] * 512;
  }
#pragma unroll
  for (int j = 0; j < 4; ++j)     // chunk 0 gather
    G0[j] = *(const unsigned int*)(xbc + cibC[j] + cg * 4);
#pragma unroll
  for (int j = 0; j < 4; ++j)     // chunk 1 gather
    G1[j] = *(const unsigned int*)(xbc + cibC[j] + 64 + cg * 4);
#pragma unroll
  for (int i = 0; i < 2; ++i) B0[i] = wp[(bfo + i) * 64 + lane];
#pragma unroll
  for (int i = 0; i < 2; ++i) B1[i] = wp[(16 + bfo + i) * 64 + lane];

#define COMBINE_STORE(Gx, buf)                                              \
  {                                                                         \
    float s0 = cwrC[0] * __uint_as_float(Gx[0] << 16);                      \
    float s1 = cwrC[0] * __uint_as_float(Gx[0] & 0xffff0000u);              \
    s0 = fmaf(cwrC[1], __uint_as_float(Gx[1] << 16), s0);                   \
    s1 = fmaf(cwrC[1], __uint_as_float(Gx[1] & 0xffff0000u), s1);           \
    s0 = fmaf(cwrC[2], __uint_as_float(Gx[2] << 16), s0);                   \
    s1 = fmaf(cwrC[2], __uint_as_float(Gx[2] & 0xffff0000u), s1);           \
    s0 = fmaf(cwrC[3], __uint_as_float(Gx[3] << 16), s0);                   \
    s1 = fmaf(cwrC[3], __uint_as_float(Gx[3] & 0xffff0000u), s1);           \
    const unsigned int h0 = f2bf_bits(s0), h1 = f2bf_bits(s1);              \
    const unsigned int l0 = f2bf_bits(s0 - __uint_as_float(h0 << 16));      \
    const unsigned int l1 = f2bf_bits(s1 - __uint_as_float(h1 << 16));      \
    *(unsigned int*)(sAb + (buf) * 4096 + wbA) = h0 | (h1 << 16);           \
    *(unsigned int*)(sAb + (buf) * 4096 + wbL) = l0 | (l1 << 16);           \
  }

#define MFMA_BODY(buf, Bx)                                                  \
  {                                                                         \
    bf16x8 ah[2], al[2];                                                    \
    ah[0] = __builtin_bit_cast(                                             \
        bf16x8, *(const u16x8*)(sAb + (buf) * 4096 + rb0));                 \
    al[0] = __builtin_bit_cast(                                             \
        bf16x8, *(const u16x8*)(sAb + (buf) * 4096 + (rb0 ^ 64)));          \
    ah[1] = __builtin_bit_cast(                                             \
        bf16x8, *(const u16x8*)(sAb + (buf) * 4096 + rb1));                 \
    al[1] = __builtin_bit_cast(                                             \
        bf16x8, *(const u16x8*)(sAb + (buf) * 4096 + (rb1 ^ 64)));          \
    _Pragma("unroll") for (int nt = 0; nt < 2; ++nt) {                      \
      const bf16x8 bv = __builtin_bit_cast(bf16x8, Bx[nt]);                 \
      _Pragma("unroll") for (int mt = 0; mt < 2; ++mt) {                    \
        acc[mt][nt] = __builtin_amdgcn_mfma_f32_16x16x32_bf16(              \
            ah[mt], bv, acc[mt][nt], 0, 0, 0);                              \
        acc[mt][nt] = __builtin_amdgcn_mfma_f32_16x16x32_bf16(              \
            al[mt], bv, acc[mt][nt], 0, 0, 0);                              \
      }                                                                     \
    }                                                                       \
  }

  for (int k9 = 0; k9 < 9; ++k9) {
    const int cbase = k9 * 8;
#pragma unroll
    for (int j4 = 0; j4 < 4; ++j4) {
      // ---- body A: chunk cbase+2*j4 -> buf0; prefetch chunk +2 -> G0/B0
      COMBINE_STORE(G0, 0)
      __syncthreads();
      if (k9 < 8 || j4 < 3) {
        if (j4 == 3) {           // prefetch crosses into tap k9+1
#pragma unroll
          for (int j = 0; j < 4; ++j) {
            cwrN[j] = s_cw[((k9 + 1) * 4 + j) * 32 + sm];
            cibN[j] = s_ci[((k9 + 1) * 4 + j) * 32 + sm] * 512;
          }
#pragma unroll
          for (int j = 0; j < 4; ++j)
            G0[j] = *(const unsigned int*)(xbc + cibN[j] + cg * 4);
        } else {
          const int c0b = (2 * j4 + 2) * 64 + cg * 4;
#pragma unroll
          for (int j = 0; j < 4; ++j)
            G0[j] = *(const unsigned int*)(xbc + cibC[j] + c0b);
        }
      }
      MFMA_BODY(0, B0)
      if (k9 < 8 || j4 < 3) {
        const int c2 = cbase + 2 * j4 + 2;
#pragma unroll
        for (int i = 0; i < 2; ++i)
          B0[i] = wp[(c2 * 16 + bfo + i) * 64 + lane];
      }
      // ---- body B: chunk cbase+2*j4+1 -> buf1; prefetch chunk +2 -> G1/B1
      COMBINE_STORE(G1, 1)
      __syncthreads();
      if (k9 < 8 || j4 < 3) {
        if (j4 == 3) {
#pragma unroll
          for (int j = 0; j < 4; ++j)
            G1[j] = *(const unsigned int*)(xbc + cibN[j] + 64 + cg * 4);
        } else {
          const int c1b = (2 * j4 + 3) * 64 + cg * 4;
#pragma unroll
          for (int j = 0; j < 4; ++j)
            G1[j] = *(const unsigned int*)(xbc + cibC[j] + c1b);
        }
      }
      MFMA_BODY(1, B1)
      if (k9 < 8 || j4 < 3) {
        const int c3 = cbase + 2 * j4 + 3;
#pragma unroll
        for (int i = 0; i < 2; ++i)
          B1[i] = wp[(c3 * 16 + bfo + i) * 64 + lane];
      }
      if (j4 == 3 && k9 < 8) {   // advance combine tap params
#pragma unroll
        for (int j = 0; j < 4; ++j) { cwrC[j] = cwrN[j]; cibC[j] = cibN[j]; }
      }
    }
  }
#undef COMBINE_STORE
#undef MFMA_BODY

  if (outf) {
    // final layer: ReLU + direct fp32 NCHW scatter (float4 per tile-row)
#pragma unroll
    for (int mt = 0; mt < 2; ++mt)
#pragma unroll
      for (int nt = 0; nt < 2; ++nt) {
        const int n = wv * 32 + nt * 16 + frow;
        const int pos = h * 64 + w0 + mt * 16 + quad * 4;
        float4 vv;
        vv.x = fmaxf(acc[mt][nt][0], 0.f);
        vv.y = fmaxf(acc[mt][nt][1], 0.f);
        vv.z = fmaxf(acc[mt][nt][2], 0.f);
        vv.w = fmaxf(acc[mt][nt][3], 0.f);
        *(float4*)&outf[(size_t)(b * 256 + n) * HW + pos] = vv;
      }
  } else {
    // layers 0-2: ReLU + bf16-hi transposed plane via per-wave LDS slice
    __syncthreads();   // all K-loop smem/sA traffic done before union reuse
    unsigned short* sW = (unsigned short*)smem + wv * (32 * 36);  // [32][36]
#pragma unroll
    for (int mt = 0; mt < 2; ++mt)
#pragma unroll
      for (int nt = 0; nt < 2; ++nt)
#pragma unroll
        for (int r = 0; r < 4; ++r)
          sW[(mt * 16 + quad * 4 + r) * 36 + nt * 16 + frow] =
              (unsigned short)f2bf_bits(fmaxf(acc[mt][nt][r], 0.f));
    __syncthreads();
    const int lm = lane & 31, cg2 = lane >> 5;
    const int pos = h * 64 + w0 + lm;
    unsigned short* __restrict__ yp =
        yth + ((size_t)b * HW + pos) * 256 + wv * 32 + cg2 * 16;
#pragma unroll
    for (int g = 0; g < 2; ++g)
      *(u16x8*)(yp + g * 8) = *(const u16x8*)&sW[lm * 36 + cg2 * 16 + g * 8];
  }
}

extern "C" void kernel_launch(void* const* d_in, const int* in_sizes, int n_in,
                              void* d_out, int out_size, void* d_ws, size_t ws_size,
                              hipStream_t stream) {
  const float* x0   = (const float*)d_in[0];  // [4][256][64][64]
  const float* offw = (const float*)d_in[1];  // [4][18][256][3][3]
  const float* offb = (const float*)d_in[2];  // [4][18]
  const float* w    = (const float*)d_in[3];  // [4][256][256][3][3]
  float* out = (float*)d_out;                 // [4][256][64][64]
  float* ws  = (float*)d_ws;

  float* offs = ws;                                     //   294,912 floats
  unsigned short* wph  = (unsigned short*)(ws + 294912);    // 2,359,296 ushort
  unsigned short* owph = wph + 2359296;                     //   294,912 ushort
  unsigned short* xTA  = owph + 294912;                     // 4,194,304 ushort
  unsigned short* xTB  = xTA + 4194304;                     // 4,194,304 ushort

  wpack_kernel<<<9216, 256, 0, stream>>>(w, wph);
  offwpack_kernel<<<1152, 256, 0, stream>>>(offw, owph);
  xpose_kernel<<<dim3(64, 4, 4), 256, 0, stream>>>(x0, xTA);

  unsigned short* pin = xTA;
  unsigned short* pout = xTB;
  for (int r = 0; r < 4; ++r) {
    offconv_mfma<<<512, 512, 0, stream>>>(pin, owph + r * 73728,
                                          offb + r * 18, offs);
    deform_mfma<<<512, 512, 0, stream>>>(pin, offs,
                                         wph + (size_t)r * 589824,
                                         (r < 3) ? pout : nullptr,
                                         (r < 3) ? nullptr : out);
    unsigned short* tmp = pin; pin = pout; pout = tmp;
  }
}

// Round 4
// 357.575 us; speedup vs baseline: 1.3948x; 1.0167x over previous
//
#include <hip/hip_runtime.h>

// RepetHead: 4 layers of (3x3 offset conv -> DCNv1 deform conv -> ReLU)
// B=4, C=256, H=W=64, K=9 taps.
// Round 10: deform K-loop barriers lose their vmcnt(0) drain. __syncthreads
// emits "s_waitcnt vmcnt(0) lgkmcnt(0); s_barrier", force-draining the
// 2-chunk-ahead gather/B prefetches at every barrier (72x/block) and
// capping prefetch distance at one body. The LDS double-buffer only needs
// lgkm ordering: each wave's buf reads complete under its own lgkmcnt(0)
// before the barrier, so WAR on the buffer stays safe. Replaced with
// raw "s_waitcnt lgkmcnt(0); s_barrier; sched_barrier(0)" (HK pattern).
// Also: s_setprio(1) around the MFMA cluster (T5; 4 waves/SIMD from 2
// independent blocks = role diversity). R9 learning: SQ_LDS_BANK_CONFLICT
// = exactly 5.0/ds_read_b128 = intrinsic b128 bank aliasing, not fixable.
//
// ws layout (floats):
//   offs :   294,912
//   wph  : 1,179,648  (2,359,296 ushort, deform B frag-packed, bf16-hi)
//   owph :   147,456  (  294,912 ushort, offset-conv B frag-packed)
//   xTA  : 2,097,152  (4,194,304 ushort, plane ping)
//   xTB  : 2,097,152  (4,194,304 ushort, plane pong)
// total 5,816,320 floats = 23.3 MB

#define HW 4096

typedef __attribute__((ext_vector_type(8))) __bf16 bf16x8;
typedef __attribute__((ext_vector_type(4))) float f32x4;
typedef __attribute__((ext_vector_type(8))) unsigned short u16x8;

__device__ inline unsigned int f2bf_bits(float f) {
  unsigned int u = __float_as_uint(f);
  return (u + 0x7fffu + ((u >> 16) & 1u)) >> 16;   // RNE to bf16
}
__device__ inline float bf_hi_f(unsigned short h) {
  return __uint_as_float(((unsigned int)h) << 16);
}

// Workgroup barrier with LDS-only ordering: no vmcnt drain, so global
// prefetches stay in flight across it. sched_barrier pins ds_read motion.
__device__ inline void wg_barrier_lds() {
  asm volatile("s_waitcnt lgkmcnt(0)" ::: "memory");
  __builtin_amdgcn_s_barrier();
  __builtin_amdgcn_sched_barrier(0);
}

// ---------------------------------------------------------------------------
// w[r][o][c][ky][kx] -> frag-packed wph[r][q=72][nt=16][lane=64][j=8] (bf16-hi)
// n = nt*16+(lane&15); kk = q*32+(lane>>4)*8+j; c = kk&255; k = kk>>8.
__global__ __launch_bounds__(256) void wpack_kernel(
    const float* __restrict__ w, unsigned short* __restrict__ wph) {
  const int f = blockIdx.x * 256 + threadIdx.x;   // < 2,359,296
  const int j  = f & 7;
  const int l  = (f >> 3) & 63;
  const int nt = (f >> 9) & 15;
  const int q  = (f >> 13) % 72;
  const int r  = f / 589824;
  const int n  = nt * 16 + (l & 15);
  const int kk = q * 32 + ((l >> 4) << 3) + j;
  const int c  = kk & 255, k = kk >> 8;
  wph[f] = (unsigned short)f2bf_bits(w[((r * 256 + n) * 256 + c) * 9 + k]);
}

// offw[r][18][256][3][3] -> owph[r][q=72][nt=2][lane=64][j=8] (n>=18 -> 0)
__global__ __launch_bounds__(256) void offwpack_kernel(
    const float* __restrict__ offw, unsigned short* __restrict__ owph) {
  const int f = blockIdx.x * 256 + threadIdx.x;   // < 294,912
  const int j  = f & 7;
  const int l  = (f >> 3) & 63;
  const int nt = (f >> 9) & 1;
  const int q  = (f >> 10) % 72;
  const int r  = f / 73728;
  const int n  = nt * 16 + (l & 15);
  const int kk = q * 32 + ((l >> 4) << 3) + j;
  const int c  = kk & 255, k = kk >> 8;
  const float v = (n < 18) ? offw[((r * 18 + n) * 256 + c) * 9 + k] : 0.f;
  owph[f] = (unsigned short)f2bf_bits(v);
}

// ---------------------------------------------------------------------------
// x [4][256][4096] fp32 -> xT [4][4096][256] bf16-hi (transpose + cast)
__global__ __launch_bounds__(256) void xpose_kernel(
    const float* __restrict__ x, unsigned short* __restrict__ xh) {
  const int p0 = blockIdx.x * 64;     // pos tile
  const int c0 = blockIdx.y * 64;     // channel tile
  const int b  = blockIdx.z;
  __shared__ float sT[64][65];
  const int t = threadIdx.x;
  const int pj = t & 63, ci0 = (t >> 6) * 16;
  const float* __restrict__ xb = x + ((size_t)(b * 256 + c0)) * HW + p0;
#pragma unroll
  for (int u = 0; u < 16; ++u)
    sT[ci0 + u][pj] = xb[(size_t)(ci0 + u) * HW + pj];
  __syncthreads();
  const int pr = t >> 2, cs = (t & 3) * 16;
  u16x8 va, vb;
#pragma unroll
  for (int u = 0; u < 8; ++u) va[u] = (unsigned short)f2bf_bits(sT[cs + u][pr]);
#pragma unroll
  for (int u = 0; u < 8; ++u) vb[u] = (unsigned short)f2bf_bits(sT[cs + 8 + u][pr]);
  const size_t o = ((size_t)b * HW + p0 + pr) * 256 + c0 + cs;
  *(u16x8*)(xh + o) = va;
  *(u16x8*)(xh + o + 8) = vb;
}

// ---------------------------------------------------------------------------
// Offset conv, zero-LDS MFMA main loop. 512 threads = 8 waves:
// (mt, nt, kv) = (wv&1, (wv>>1)&1, wv>>2); K split across kv halves
// (cc = kv*4 + j), combined via an LDS f32x4 reduction at the end.
__global__ __launch_bounds__(512) void offconv_mfma(
    const unsigned short* __restrict__ xh,
    const unsigned short* __restrict__ owh,
    const float* __restrict__ bias, float* __restrict__ offs) {
  const int gid = blockIdx.x;                 // 0..511
  const int b = (gid & 7) >> 1;
  const int idx = ((gid >> 3) << 1) | (gid & 1);   // 0..127
  const int h = idx >> 1, w0 = (idx & 1) << 5;
  const int t = threadIdx.x, lane = t & 63, wv = t >> 6;
  const int frow = lane & 15, fgrp = lane >> 4;
  const int mt = wv & 1, nt = (wv >> 1) & 1, kv = wv >> 2;
  const int m = w0 + mt * 16 + frow;          // w coordinate of A row

  f32x4 acc = {0.f, 0.f, 0.f, 0.f};
  const u16x8 z8 = {};
  const size_t xb = (size_t)b * HW;

  for (int k = 0; k < 9; ++k) {
    const int ky = k / 3 - 1, kx = k % 3 - 1;
    if ((unsigned)(h + ky) < 64u) {           // block-uniform branch
      const bool vpx = (unsigned)(m + kx) < 64u;
      const int cpx = (m + kx) < 0 ? 0 : ((m + kx) > 63 ? 63 : (m + kx));
      const size_t abase = (xb + (size_t)((h + ky) * 64 + cpx)) * 256 + fgrp * 8;
#pragma unroll
      for (int j = 0; j < 4; ++j) {
        const int cc = kv * 4 + j;
        const int q = k * 8 + cc;
        u16x8 ahr = *(const u16x8*)(xh + abase + cc * 32);
        if (!vpx) ahr = z8;
        const u16x8 bhr = ((const u16x8*)owh)[(q * 2 + nt) * 64 + lane];
        const bf16x8 ah = __builtin_bit_cast(bf16x8, ahr);
        const bf16x8 bh = __builtin_bit_cast(bf16x8, bhr);
        acc = __builtin_amdgcn_mfma_f32_16x16x32_bf16(ah, bh, acc, 0, 0, 0);
      }
    }
  }

  __shared__ f32x4 red[2][2][64];             // [mt][nt][lane]
  if (kv == 1) red[mt][nt][lane] = acc;
  __syncthreads();
  if (kv == 0) {
    const f32x4 o = red[mt][nt][lane];
    acc[0] += o[0]; acc[1] += o[1]; acc[2] += o[2]; acc[3] += o[3];
    const int oc = nt * 16 + frow;            // C/D: col = lane&15 -> n
    if (oc < 18) {
      const float bv = bias[oc];
      const int wbase = w0 + mt * 16 + fgrp * 4;  // C/D row = (lane>>4)*4 + r
      float* __restrict__ op =
          offs + (size_t)(b * 18 + oc) * HW + h * 64 + wbase;
#pragma unroll
      for (int r = 0; r < 4; ++r) op[r] = acc[r] + bv;
    }
  }
}

// ---------------------------------------------------------------------------
// Fused bilinear-sample + bf16 MFMA GEMM + ReLU. Block: M=32 (half row),
// N=256, 512 threads = 8 waves (each wave 2 m-tiles x 2 n-tiles x hi/lo).
// Staging LDS: [buf][32 rows][128 B], slot ^= g(row). K-loop barriers are
// lgkm-only (no vmcnt drain) so gather/B prefetches ride across them;
// MFMA cluster wrapped in s_setprio(1)/(0).
__global__ __launch_bounds__(512, 4) void deform_mfma(
    const unsigned short* __restrict__ xh,   // [4][4096][256] bf16-hi plane
    const float* __restrict__ offs,          // [4][18][4096]
    const unsigned short* __restrict__ wph,  // [72][16][64][8] this layer
    unsigned short* __restrict__ yth,        // next plane (layers 0-2)
    float* __restrict__ outf) {              // fp32 NCHW out (layer 3)
  const int gid = blockIdx.x;                  // 0..511
  const int b = (gid & 7) >> 1;                // 2 XCDs per batch image
  const int idx = ((gid >> 3) << 1) | (gid & 1);   // 0..127
  const int h = idx >> 1, w0 = (idx & 1) << 5;     // half-row of 32
  const int t = threadIdx.x, lane = t & 63, wv = t >> 6;   // 8 waves
  const int frow = lane & 15, quad = lane >> 4;
  const int sm = t >> 4, cg = t & 15;          // staging: row 0..31, pair 0..15

  __shared__ __align__(16) unsigned char smem[18432];
  float* s_cw = (float*)smem;                  // [9][4][32] = 4608 B
  int*   s_ci = (int*)(smem + 4608);           // [9][4][32] = 4608 B
  unsigned char* sAb = smem + 9216;            // [2][32][128 B] = 8192 B

  // phase 0: per (k, m) bilinear setup, m = w coordinate within half-row
  for (int i = t; i < 288; i += 512) {
    const int k = i >> 5, m = i & 31;
    const int ky = k / 3 - 1, kx = k % 3 - 1;
    const int mw = w0 + m;
    const int pos = h * 64 + mw;
    const float dy = offs[(b * 18 + 2 * k) * HW + pos];
    const float dx = offs[(b * 18 + 2 * k + 1) * HW + pos];
    const float py = (float)(h + ky) + dy;
    const float px = (float)(mw + kx) + dx;
    const float y0f = floorf(py), x0f = floorf(px);
    const float wy = py - y0f, wx = px - x0f;
    const int y0 = (int)y0f, x0 = (int)x0f;
#pragma unroll
    for (int j = 0; j < 4; ++j) {
      const int yi = y0 + (j >> 1), xi = x0 + (j & 1);
      const bool v = (yi >= 0) && (yi < 64) && (xi >= 0) && (xi < 64);
      const float wgt = ((j >> 1) ? wy : 1.f - wy) * ((j & 1) ? wx : 1.f - wx);
      s_cw[(k * 4 + j) * 32 + m] = v ? wgt : 0.f;
      const int yc = yi < 0 ? 0 : (yi > 63 ? 63 : yi);
      const int xc = xi < 0 ? 0 : (xi > 63 ? 63 : xi);
      s_ci[(k * 4 + j) * 32 + m] = yc * 64 + xc;
    }
  }
  __syncthreads();

  f32x4 acc[2][2];
#pragma unroll
  for (int mt = 0; mt < 2; ++mt)
#pragma unroll
    for (int nt = 0; nt < 2; ++nt) acc[mt][nt] = (f32x4){0.f, 0.f, 0.f, 0.f};

  const char* __restrict__ xbc = (const char*)(xh + (size_t)b * HW * 256);
  const u16x8* __restrict__ wp = (const u16x8*)wph;
  const int bfo = wv * 2;                      // wave's n-tile base (0..14)

  // XOR-swizzled staging addresses (loop-invariant).
  const int gs = ((sm & 3) << 1) | ((sm >> 2) & 1);
  const int wbA = sm * 128 + ((((cg >> 2) ^ gs)) << 4) + (cg & 3) * 4;  // hi
  const int wbL = wbA ^ 64;                                            // lo
  const int gr = ((frow & 3) << 1) | ((frow >> 2) & 1);
  const int rb0 = frow * 128 + ((quad ^ gr) << 4);        // mt=0 hi
  const int rb1 = rb0 + 2048;                             // mt=1 hi

  unsigned int G0[4], G1[4];
  u16x8 B0[2], B1[2];
  float cwrC[4], cwrN[4];
  int cibC[4], cibN[4];
#pragma unroll
  for (int j = 0; j < 4; ++j) {   // tap 0 staging params (byte offsets)
    cwrC[j] = s_cw[j * 32 + sm];
    cibC[j] = s_ci[j * 32 + sm] * 512;
  }
#pragma unroll
  for (int j = 0; j < 4; ++j)     // chunk 0 gather
    G0[j] = *(const unsigned int*)(xbc + cibC[j] + cg * 4);
#pragma unroll
  for (int j = 0; j < 4; ++j)     // chunk 1 gather
    G1[j] = *(const unsigned int*)(xbc + cibC[j] + 64 + cg * 4);
#pragma unroll
  for (int i = 0; i < 2; ++i) B0[i] = wp[(bfo + i) * 64 + lane];
#pragma unroll
  for (int i = 0; i < 2; ++i) B1[i] = wp[(16 + bfo + i) * 64 + lane];

#define COMBINE_STORE(Gx, buf)                                              \
  {                                                                         \
    float s0 = cwrC[0] * __uint_as_float(Gx[0] << 16);                      \
    float s1 = cwrC[0] * __uint_as_float(Gx[0] & 0xffff0000u);              \
    s0 = fmaf(cwrC[1], __uint_as_float(Gx[1] << 16), s0);                   \
    s1 = fmaf(cwrC[1], __uint_as_float(Gx[1] & 0xffff0000u), s1);           \
    s0 = fmaf(cwrC[2], __uint_as_float(Gx[2] << 16), s0);                   \
    s1 = fmaf(cwrC[2], __uint_as_float(Gx[2] & 0xffff0000u), s1);           \
    s0 = fmaf(cwrC[3], __uint_as_float(Gx[3] << 16), s0);                   \
    s1 = fmaf(cwrC[3], __uint_as_float(Gx[3] & 0xffff0000u), s1);           \
    const unsigned int h0 = f2bf_bits(s0), h1 = f2bf_bits(s1);              \
    const unsigned int l0 = f2bf_bits(s0 - __uint_as_float(h0 << 16));      \
    const unsigned int l1 = f2bf_bits(s1 - __uint_as_float(h1 << 16));      \
    *(unsigned int*)(sAb + (buf) * 4096 + wbA) = h0 | (h1 << 16);           \
    *(unsigned int*)(sAb + (buf) * 4096 + wbL) = l0 | (l1 << 16);           \
  }

#define MFMA_BODY(buf, Bx)                                                  \
  {                                                                         \
    bf16x8 ah[2], al[2];                                                    \
    ah[0] = __builtin_bit_cast(                                             \
        bf16x8, *(const u16x8*)(sAb + (buf) * 4096 + rb0));                 \
    al[0] = __builtin_bit_cast(                                             \
        bf16x8, *(const u16x8*)(sAb + (buf) * 4096 + (rb0 ^ 64)));          \
    ah[1] = __builtin_bit_cast(                                             \
        bf16x8, *(const u16x8*)(sAb + (buf) * 4096 + rb1));                 \
    al[1] = __builtin_bit_cast(                                             \
        bf16x8, *(const u16x8*)(sAb + (buf) * 4096 + (rb1 ^ 64)));          \
    __builtin_amdgcn_s_setprio(1);                                          \
    _Pragma("unroll") for (int nt = 0; nt < 2; ++nt) {                      \
      const bf16x8 bv = __builtin_bit_cast(bf16x8, Bx[nt]);                 \
      _Pragma("unroll") for (int mt = 0; mt < 2; ++mt) {                    \
        acc[mt][nt] = __builtin_amdgcn_mfma_f32_16x16x32_bf16(              \
            ah[mt], bv, acc[mt][nt], 0, 0, 0);                              \
        acc[mt][nt] = __builtin_amdgcn_mfma_f32_16x16x32_bf16(              \
            al[mt], bv, acc[mt][nt], 0, 0, 0);                              \
      }                                                                     \
    }                                                                       \
    __builtin_amdgcn_s_setprio(0);                                          \
  }

  for (int k9 = 0; k9 < 9; ++k9) {
    const int cbase = k9 * 8;
#pragma unroll
    for (int j4 = 0; j4 < 4; ++j4) {
      // ---- body A: chunk cbase+2*j4 -> buf0; prefetch chunk +2 -> G0/B0
      COMBINE_STORE(G0, 0)
      wg_barrier_lds();
      if (k9 < 8 || j4 < 3) {
        if (j4 == 3) {           // prefetch crosses into tap k9+1
#pragma unroll
          for (int j = 0; j < 4; ++j) {
            cwrN[j] = s_cw[((k9 + 1) * 4 + j) * 32 + sm];
            cibN[j] = s_ci[((k9 + 1) * 4 + j) * 32 + sm] * 512;
          }
#pragma unroll
          for (int j = 0; j < 4; ++j)
            G0[j] = *(const unsigned int*)(xbc + cibN[j] + cg * 4);
        } else {
          const int c0b = (2 * j4 + 2) * 64 + cg * 4;
#pragma unroll
          for (int j = 0; j < 4; ++j)
            G0[j] = *(const unsigned int*)(xbc + cibC[j] + c0b);
        }
      }
      MFMA_BODY(0, B0)
      if (k9 < 8 || j4 < 3) {
        const int c2 = cbase + 2 * j4 + 2;
#pragma unroll
        for (int i = 0; i < 2; ++i)
          B0[i] = wp[(c2 * 16 + bfo + i) * 64 + lane];
      }
      // ---- body B: chunk cbase+2*j4+1 -> buf1; prefetch chunk +2 -> G1/B1
      COMBINE_STORE(G1, 1)
      wg_barrier_lds();
      if (k9 < 8 || j4 < 3) {
        if (j4 == 3) {
#pragma unroll
          for (int j = 0; j < 4; ++j)
            G1[j] = *(const unsigned int*)(xbc + cibN[j] + 64 + cg * 4);
        } else {
          const int c1b = (2 * j4 + 3) * 64 + cg * 4;
#pragma unroll
          for (int j = 0; j < 4; ++j)
            G1[j] = *(const unsigned int*)(xbc + cibC[j] + c1b);
        }
      }
      MFMA_BODY(1, B1)
      if (k9 < 8 || j4 < 3) {
        const int c3 = cbase + 2 * j4 + 3;
#pragma unroll
        for (int i = 0; i < 2; ++i)
          B1[i] = wp[(c3 * 16 + bfo + i) * 64 + lane];
      }
      if (j4 == 3 && k9 < 8) {   // advance combine tap params
#pragma unroll
        for (int j = 0; j < 4; ++j) { cwrC[j] = cwrN[j]; cibC[j] = cibN[j]; }
      }
    }
  }
#undef COMBINE_STORE
#undef MFMA_BODY

  if (outf) {
    // final layer: ReLU + direct fp32 NCHW scatter (float4 per tile-row)
#pragma unroll
    for (int mt = 0; mt < 2; ++mt)
#pragma unroll
      for (int nt = 0; nt < 2; ++nt) {
        const int n = wv * 32 + nt * 16 + frow;
        const int pos = h * 64 + w0 + mt * 16 + quad * 4;
        float4 vv;
        vv.x = fmaxf(acc[mt][nt][0], 0.f);
        vv.y = fmaxf(acc[mt][nt][1], 0.f);
        vv.z = fmaxf(acc[mt][nt][2], 0.f);
        vv.w = fmaxf(acc[mt][nt][3], 0.f);
        *(float4*)&outf[(size_t)(b * 256 + n) * HW + pos] = vv;
      }
  } else {
    // layers 0-2: ReLU + bf16-hi transposed plane via per-wave LDS slice
    __syncthreads();   // full drain before smem union reuse
    unsigned short* sW = (unsigned short*)smem + wv * (32 * 36);  // [32][36]
#pragma unroll
    for (int mt = 0; mt < 2; ++mt)
#pragma unroll
      for (int nt = 0; nt < 2; ++nt)
#pragma unroll
        for (int r = 0; r < 4; ++r)
          sW[(mt * 16 + quad * 4 + r) * 36 + nt * 16 + frow] =
              (unsigned short)f2bf_bits(fmaxf(acc[mt][nt][r], 0.f));
    __syncthreads();
    const int lm = lane & 31, cg2 = lane >> 5;
    const int pos = h * 64 + w0 + lm;
    unsigned short* __restrict__ yp =
        yth + ((size_t)b * HW + pos) * 256 + wv * 32 + cg2 * 16;
#pragma unroll
    for (int g = 0; g < 2; ++g)
      *(u16x8*)(yp + g * 8) = *(const u16x8*)&sW[lm * 36 + cg2 * 16 + g * 8];
  }
}

extern "C" void kernel_launch(void* const* d_in, const int* in_sizes, int n_in,
                              void* d_out, int out_size, void* d_ws, size_t ws_size,
                              hipStream_t stream) {
  const float* x0   = (const float*)d_in[0];  // [4][256][64][64]
  const float* offw = (const float*)d_in[1];  // [4][18][256][3][3]
  const float* offb = (const float*)d_in[2];  // [4][18]
  const float* w    = (const float*)d_in[3];  // [4][256][256][3][3]
  float* out = (float*)d_out;                 // [4][256][64][64]
  float* ws  = (float*)d_ws;

  float* offs = ws;                                     //   294,912 floats
  unsigned short* wph  = (unsigned short*)(ws + 294912);    // 2,359,296 ushort
  unsigned short* owph = wph + 2359296;                     //   294,912 ushort
  unsigned short* xTA  = owph + 294912;                     // 4,194,304 ushort
  unsigned short* xTB  = xTA + 4194304;                     // 4,194,304 ushort

  wpack_kernel<<<9216, 256, 0, stream>>>(w, wph);
  offwpack_kernel<<<1152, 256, 0, stream>>>(offw, owph);
  xpose_kernel<<<dim3(64, 4, 4), 256, 0, stream>>>(x0, xTA);

  unsigned short* pin = xTA;
  unsigned short* pout = xTB;
  for (int r = 0; r < 4; ++r) {
    offconv_mfma<<<512, 512, 0, stream>>>(pin, owph + r * 73728,
                                          offb + r * 18, offs);
    deform_mfma<<<512, 512, 0, stream>>>(pin, offs,
                                         wph + (size_t)r * 589824,
                                         (r < 3) ? pout : nullptr,
                                         (r < 3) ? nullptr : out);
    unsigned short* tmp = pin; pin = pout; pout = tmp;
  }
}

// Round 5
// 346.848 us; speedup vs baseline: 1.4380x; 1.0309x over previous
//
#include <hip/hip_runtime.h>

// RepetHead: 4 layers of (3x3 offset conv -> DCNv1 deform conv -> ReLU)
// B=4, C=256, H=W=64, K=9 taps.
// Round 11:
//  (a) deform: 2-chunk super-bodies -- one barrier per 2 chunks (36/block
//      instead of 72), 4 x 4KB LDS sub-buffers in 2 double-buffered pairs.
//      Same WAR safety: reuse distance = 2 barriers.
//  (b) deform COMBINE: native (__bf16) casts (v_cvt_pk_bf16_f32, RNE ==
//      old integer emulation bit-for-bit) instead of 4-op-per-value
//      integer RNE: ~38 -> ~24 VALU per combine.
//  (c) offconv: fully-unrolled 9-tap body with literal A0/B0 <-> A1/B1
//      register double-buffering (loads for tap k+2 issued after tap k's
//      MFMAs); row-invalid taps folded into the zero mask (no 'continue').
// R10 learning: barrier vmcnt-drain was NOT the stall (lgkm-only barrier
// neutral). R9 learning: SQ_LDS_BANK_CONFLICT = 5.0/ds_read_b128 is
// intrinsic b128 bank aliasing, not fixable by swizzle.
//
// ws layout (floats):
//   offs :   294,912
//   wph  : 1,179,648  (2,359,296 ushort, deform B frag-packed, bf16-hi)
//   owph :   147,456  (  294,912 ushort, offset-conv B frag-packed)
//   xTA  : 2,097,152  (4,194,304 ushort, plane ping)
//   xTB  : 2,097,152  (4,194,304 ushort, plane pong)
// total 5,816,320 floats = 23.3 MB

#define HW 4096

typedef __attribute__((ext_vector_type(8))) __bf16 bf16x8;
typedef __attribute__((ext_vector_type(4))) float f32x4;
typedef __attribute__((ext_vector_type(8))) unsigned short u16x8;

__device__ inline unsigned int f2bf_bits(float f) {
  unsigned int u = __float_as_uint(f);
  return (u + 0x7fffu + ((u >> 16) & 1u)) >> 16;   // RNE to bf16
}
__device__ inline float bf_hi_f(unsigned short h) {
  return __uint_as_float(((unsigned int)h) << 16);
}

// Workgroup barrier with LDS-only ordering: no vmcnt drain, so global
// prefetches stay in flight across it. sched_barrier pins ds_read motion.
__device__ inline void wg_barrier_lds() {
  asm volatile("s_waitcnt lgkmcnt(0)" ::: "memory");
  __builtin_amdgcn_s_barrier();
  __builtin_amdgcn_sched_barrier(0);
}

// ---------------------------------------------------------------------------
// w[r][o][c][ky][kx] -> frag-packed wph[r][q=72][nt=16][lane=64][j=8] (bf16-hi)
// n = nt*16+(lane&15); kk = q*32+(lane>>4)*8+j; c = kk&255; k = kk>>8.
__global__ __launch_bounds__(256) void wpack_kernel(
    const float* __restrict__ w, unsigned short* __restrict__ wph) {
  const int f = blockIdx.x * 256 + threadIdx.x;   // < 2,359,296
  const int j  = f & 7;
  const int l  = (f >> 3) & 63;
  const int nt = (f >> 9) & 15;
  const int q  = (f >> 13) % 72;
  const int r  = f / 589824;
  const int n  = nt * 16 + (l & 15);
  const int kk = q * 32 + ((l >> 4) << 3) + j;
  const int c  = kk & 255, k = kk >> 8;
  wph[f] = (unsigned short)f2bf_bits(w[((r * 256 + n) * 256 + c) * 9 + k]);
}

// offw[r][18][256][3][3] -> owph[r][q=72][nt=2][lane=64][j=8] (n>=18 -> 0)
__global__ __launch_bounds__(256) void offwpack_kernel(
    const float* __restrict__ offw, unsigned short* __restrict__ owph) {
  const int f = blockIdx.x * 256 + threadIdx.x;   // < 294,912
  const int j  = f & 7;
  const int l  = (f >> 3) & 63;
  const int nt = (f >> 9) & 1;
  const int q  = (f >> 10) % 72;
  const int r  = f / 73728;
  const int n  = nt * 16 + (l & 15);
  const int kk = q * 32 + ((l >> 4) << 3) + j;
  const int c  = kk & 255, k = kk >> 8;
  const float v = (n < 18) ? offw[((r * 18 + n) * 256 + c) * 9 + k] : 0.f;
  owph[f] = (unsigned short)f2bf_bits(v);
}

// ---------------------------------------------------------------------------
// x [4][256][4096] fp32 -> xT [4][4096][256] bf16-hi (transpose + cast)
__global__ __launch_bounds__(256) void xpose_kernel(
    const float* __restrict__ x, unsigned short* __restrict__ xh) {
  const int p0 = blockIdx.x * 64;     // pos tile
  const int c0 = blockIdx.y * 64;     // channel tile
  const int b  = blockIdx.z;
  __shared__ float sT[64][65];
  const int t = threadIdx.x;
  const int pj = t & 63, ci0 = (t >> 6) * 16;
  const float* __restrict__ xb = x + ((size_t)(b * 256 + c0)) * HW + p0;
#pragma unroll
  for (int u = 0; u < 16; ++u)
    sT[ci0 + u][pj] = xb[(size_t)(ci0 + u) * HW + pj];
  __syncthreads();
  const int pr = t >> 2, cs = (t & 3) * 16;
  u16x8 va, vb;
#pragma unroll
  for (int u = 0; u < 8; ++u) va[u] = (unsigned short)f2bf_bits(sT[cs + u][pr]);
#pragma unroll
  for (int u = 0; u < 8; ++u) vb[u] = (unsigned short)f2bf_bits(sT[cs + 8 + u][pr]);
  const size_t o = ((size_t)b * HW + p0 + pr) * 256 + c0 + cs;
  *(u16x8*)(xh + o) = va;
  *(u16x8*)(xh + o + 8) = vb;
}

// ---------------------------------------------------------------------------
// Offset conv, zero-LDS MFMA. 512 threads = 8 waves:
// (mt, nt, kv) = (wv&1, (wv>>1)&1, wv>>2); K split across kv halves,
// combined via an LDS f32x4 reduction. 9 tap bodies fully unrolled with
// literal A0/B0 <-> A1/B1 register double-buffering (prefetch ~2 bodies).
__global__ __launch_bounds__(512) void offconv_mfma(
    const unsigned short* __restrict__ xh,
    const unsigned short* __restrict__ owh,
    const float* __restrict__ bias, float* __restrict__ offs) {
  const int gid = blockIdx.x;                 // 0..511
  const int b = (gid & 7) >> 1;
  const int idx = ((gid >> 3) << 1) | (gid & 1);   // 0..127
  const int h = idx >> 1, w0 = (idx & 1) << 5;
  const int t = threadIdx.x, lane = t & 63, wv = t >> 6;
  const int frow = lane & 15, fgrp = lane >> 4;
  const int mt = wv & 1, nt = (wv >> 1) & 1, kv = wv >> 2;
  const int m = w0 + mt * 16 + frow;          // w coordinate of A row

  f32x4 acc = {0.f, 0.f, 0.f, 0.f};
  const u16x8 z8 = {};
  const size_t xb = (size_t)b * HW;
  const u16x8* __restrict__ owp = (const u16x8*)owh;

#define OLOAD(k, A, Bv)                                                     \
  {                                                                         \
    const int ky = (k) / 3 - 1, kx = (k) % 3 - 1;                           \
    const int hy = h + ky;                                                  \
    const int hyc = hy < 0 ? 0 : (hy > 63 ? 63 : hy);                       \
    const int mx = m + kx;                                                  \
    const bool v = ((unsigned)hy < 64u) && ((unsigned)mx < 64u);            \
    const int cpx = mx < 0 ? 0 : (mx > 63 ? 63 : mx);                       \
    const size_t abase =                                                    \
        (xb + (size_t)(hyc * 64 + cpx)) * 256 + fgrp * 8 + kv * 128;        \
    _Pragma("unroll") for (int j = 0; j < 4; ++j) {                         \
      A[j] = *(const u16x8*)(xh + abase + j * 32);                          \
      if (!v) A[j] = z8;                                                    \
    }                                                                       \
    _Pragma("unroll") for (int j = 0; j < 4; ++j)                           \
      Bv[j] = owp[((((k) * 8 + kv * 4 + j) * 2) + nt) * 64 + lane];         \
  }

#define OMFMA(A, Bv)                                                        \
  _Pragma("unroll") for (int j = 0; j < 4; ++j)                             \
    acc = __builtin_amdgcn_mfma_f32_16x16x32_bf16(                          \
        __builtin_bit_cast(bf16x8, A[j]), __builtin_bit_cast(bf16x8, Bv[j]),\
        acc, 0, 0, 0);

  u16x8 A0[4], Bv0[4], A1[4], Bv1[4];
  OLOAD(0, A0, Bv0)
  OLOAD(1, A1, Bv1)
  OMFMA(A0, Bv0) OLOAD(2, A0, Bv0)
  OMFMA(A1, Bv1) OLOAD(3, A1, Bv1)
  OMFMA(A0, Bv0) OLOAD(4, A0, Bv0)
  OMFMA(A1, Bv1) OLOAD(5, A1, Bv1)
  OMFMA(A0, Bv0) OLOAD(6, A0, Bv0)
  OMFMA(A1, Bv1) OLOAD(7, A1, Bv1)
  OMFMA(A0, Bv0) OLOAD(8, A0, Bv0)
  OMFMA(A1, Bv1)
  OMFMA(A0, Bv0)
#undef OLOAD
#undef OMFMA

  __shared__ f32x4 red[2][2][64];             // [mt][nt][lane]
  if (kv == 1) red[mt][nt][lane] = acc;
  __syncthreads();
  if (kv == 0) {
    const f32x4 o = red[mt][nt][lane];
    acc[0] += o[0]; acc[1] += o[1]; acc[2] += o[2]; acc[3] += o[3];
    const int oc = nt * 16 + frow;            // C/D: col = lane&15 -> n
    if (oc < 18) {
      const float bv = bias[oc];
      const int wbase = w0 + mt * 16 + fgrp * 4;  // C/D row = (lane>>4)*4 + r
      float* __restrict__ op =
          offs + (size_t)(b * 18 + oc) * HW + h * 64 + wbase;
#pragma unroll
      for (int r = 0; r < 4; ++r) op[r] = acc[r] + bv;
    }
  }
}

// ---------------------------------------------------------------------------
// Fused bilinear-sample + bf16 MFMA GEMM + ReLU. Block: M=32 (half row),
// N=256, 512 threads = 8 waves (each wave 2 m-tiles x 2 n-tiles x hi/lo).
// K-loop in 2-chunk super-bodies: combine 2 chunks -> ONE lgkm-only
// barrier -> 16 MFMA, with 4 x 4KB LDS sub-buffers (2 double-buffered
// pairs, reuse distance 2 barriers). Gather/B prefetch ~1 super ahead.
__global__ __launch_bounds__(512, 4) void deform_mfma(
    const unsigned short* __restrict__ xh,   // [4][4096][256] bf16-hi plane
    const float* __restrict__ offs,          // [4][18][4096]
    const unsigned short* __restrict__ wph,  // [72][16][64][8] this layer
    unsigned short* __restrict__ yth,        // next plane (layers 0-2)
    float* __restrict__ outf) {              // fp32 NCHW out (layer 3)
  const int gid = blockIdx.x;                  // 0..511
  const int b = (gid & 7) >> 1;                // 2 XCDs per batch image
  const int idx = ((gid >> 3) << 1) | (gid & 1);   // 0..127
  const int h = idx >> 1, w0 = (idx & 1) << 5;     // half-row of 32
  const int t = threadIdx.x, lane = t & 63, wv = t >> 6;   // 8 waves
  const int frow = lane & 15, quad = lane >> 4;
  const int sm = t >> 4, cg = t & 15;          // staging: row 0..31, pair 0..15

  __shared__ __align__(16) unsigned char smem[25600];
  float* s_cw = (float*)smem;                  // [9][4][32] = 4608 B
  int*   s_ci = (int*)(smem + 4608);           // [9][4][32] = 4608 B
  unsigned char* sAb = smem + 9216;            // 4 sub-bufs x 4096 B

  // phase 0: per (k, m) bilinear setup, m = w coordinate within half-row
  for (int i = t; i < 288; i += 512) {
    const int k = i >> 5, m = i & 31;
    const int ky = k / 3 - 1, kx = k % 3 - 1;
    const int mw = w0 + m;
    const int pos = h * 64 + mw;
    const float dy = offs[(b * 18 + 2 * k) * HW + pos];
    const float dx = offs[(b * 18 + 2 * k + 1) * HW + pos];
    const float py = (float)(h + ky) + dy;
    const float px = (float)(mw + kx) + dx;
    const float y0f = floorf(py), x0f = floorf(px);
    const float wy = py - y0f, wx = px - x0f;
    const int y0 = (int)y0f, x0 = (int)x0f;
#pragma unroll
    for (int j = 0; j < 4; ++j) {
      const int yi = y0 + (j >> 1), xi = x0 + (j & 1);
      const bool v = (yi >= 0) && (yi < 64) && (xi >= 0) && (xi < 64);
      const float wgt = ((j >> 1) ? wy : 1.f - wy) * ((j & 1) ? wx : 1.f - wx);
      s_cw[(k * 4 + j) * 32 + m] = v ? wgt : 0.f;
      const int yc = yi < 0 ? 0 : (yi > 63 ? 63 : yi);
      const int xc = xi < 0 ? 0 : (xi > 63 ? 63 : xi);
      s_ci[(k * 4 + j) * 32 + m] = yc * 64 + xc;
    }
  }
  __syncthreads();

  f32x4 acc[2][2];
#pragma unroll
  for (int mt = 0; mt < 2; ++mt)
#pragma unroll
    for (int nt = 0; nt < 2; ++nt) acc[mt][nt] = (f32x4){0.f, 0.f, 0.f, 0.f};

  const char* __restrict__ xbc = (const char*)(xh + (size_t)b * HW * 256);
  const u16x8* __restrict__ wp = (const u16x8*)wph;
  const int bfo = wv * 2;                      // wave's n-tile base (0..14)

  // XOR-swizzled staging addresses (loop-invariant, per 4KB sub-buffer).
  const int gs = ((sm & 3) << 1) | ((sm >> 2) & 1);
  const int wbA = sm * 128 + ((((cg >> 2) ^ gs)) << 4) + (cg & 3) * 4;  // hi
  const int wbL = wbA ^ 64;                                            // lo
  const int gr = ((frow & 3) << 1) | ((frow >> 2) & 1);
  const int rb0 = frow * 128 + ((quad ^ gr) << 4);        // mt=0 hi
  const int rb1 = rb0 + 2048;                             // mt=1 hi

  unsigned int G0[4], G1[4];
  u16x8 B0[2], B1[2];
  float cwrC[4], cwrN[4];
  int cibC[4], cibN[4];
#pragma unroll
  for (int j = 0; j < 4; ++j) {   // tap 0 staging params (byte offsets)
    cwrC[j] = s_cw[j * 32 + sm];
    cibC[j] = s_ci[j * 32 + sm] * 512;
  }
#pragma unroll
  for (int j = 0; j < 4; ++j)     // chunk 0 gather
    G0[j] = *(const unsigned int*)(xbc + cibC[j] + cg * 4);
#pragma unroll
  for (int j = 0; j < 4; ++j)     // chunk 1 gather
    G1[j] = *(const unsigned int*)(xbc + cibC[j] + 64 + cg * 4);
#pragma unroll
  for (int i = 0; i < 2; ++i) B0[i] = wp[(bfo + i) * 64 + lane];
#pragma unroll
  for (int i = 0; i < 2; ++i) B1[i] = wp[(16 + bfo + i) * 64 + lane];

#define COMBINE_STORE(Gx, BB)                                               \
  {                                                                         \
    float s0 = cwrC[0] * __uint_as_float(Gx[0] << 16);                      \
    float s1 = cwrC[0] * __uint_as_float(Gx[0] & 0xffff0000u);              \
    s0 = fmaf(cwrC[1], __uint_as_float(Gx[1] << 16), s0);                   \
    s1 = fmaf(cwrC[1], __uint_as_float(Gx[1] & 0xffff0000u), s1);           \
    s0 = fmaf(cwrC[2], __uint_as_float(Gx[2] << 16), s0);                   \
    s1 = fmaf(cwrC[2], __uint_as_float(Gx[2] & 0xffff0000u), s1);           \
    s0 = fmaf(cwrC[3], __uint_as_float(Gx[3] << 16), s0);                   \
    s1 = fmaf(cwrC[3], __uint_as_float(Gx[3] & 0xffff0000u), s1);           \
    const __bf16 hb0 = (__bf16)s0, hb1 = (__bf16)s1;                        \
    const unsigned int hv =                                                 \
        (unsigned int)__builtin_bit_cast(unsigned short, hb0) |             \
        ((unsigned int)__builtin_bit_cast(unsigned short, hb1) << 16);      \
    const float d0 = s0 - __uint_as_float(hv << 16);                        \
    const float d1 = s1 - __uint_as_float(hv & 0xffff0000u);                \
    const __bf16 lb0 = (__bf16)d0, lb1 = (__bf16)d1;                        \
    const unsigned int lv =                                                 \
        (unsigned int)__builtin_bit_cast(unsigned short, lb0) |             \
        ((unsigned int)__builtin_bit_cast(unsigned short, lb1) << 16);      \
    *(unsigned int*)(sAb + (BB) + wbA) = hv;                                \
    *(unsigned int*)(sAb + (BB) + wbL) = lv;                                \
  }

#define MFMA_BODY(BB, Bx)                                                   \
  {                                                                         \
    bf16x8 ah[2], al[2];                                                    \
    ah[0] = __builtin_bit_cast(bf16x8, *(const u16x8*)(sAb + (BB) + rb0));  \
    al[0] = __builtin_bit_cast(bf16x8,                                      \
                               *(const u16x8*)(sAb + (BB) + (rb0 ^ 64)));   \
    ah[1] = __builtin_bit_cast(bf16x8, *(const u16x8*)(sAb + (BB) + rb1));  \
    al[1] = __builtin_bit_cast(bf16x8,                                      \
                               *(const u16x8*)(sAb + (BB) + (rb1 ^ 64)));   \
    __builtin_amdgcn_s_setprio(1);                                          \
    _Pragma("unroll") for (int nt = 0; nt < 2; ++nt) {                      \
      const bf16x8 bv = __builtin_bit_cast(bf16x8, Bx[nt]);                 \
      _Pragma("unroll") for (int mt = 0; mt < 2; ++mt) {                    \
        acc[mt][nt] = __builtin_amdgcn_mfma_f32_16x16x32_bf16(              \
            ah[mt], bv, acc[mt][nt], 0, 0, 0);                              \
        acc[mt][nt] = __builtin_amdgcn_mfma_f32_16x16x32_bf16(              \
            al[mt], bv, acc[mt][nt], 0, 0, 0);                              \
      }                                                                     \
    }                                                                       \
    __builtin_amdgcn_s_setprio(0);                                          \
  }

  for (int k9 = 0; k9 < 9; ++k9) {
#pragma unroll
    for (int sp = 0; sp < 4; ++sp) {           // super = 2 chunks
      const int PB = (sp & 1) * 8192;          // buffer-pair byte base
      // combine chunks (k9*8 + 2*sp, +1) from regs into pair PB
      COMBINE_STORE(G0, PB)
      COMBINE_STORE(G1, PB + 4096)
      wg_barrier_lds();
      const bool more = (k9 < 8) || (sp < 3);
      if (more) {
        if (sp == 3) {         // prefetch crosses into tap k9+1
#pragma unroll
          for (int j = 0; j < 4; ++j) {
            cwrN[j] = s_cw[((k9 + 1) * 4 + j) * 32 + sm];
            cibN[j] = s_ci[((k9 + 1) * 4 + j) * 32 + sm] * 512;
          }
#pragma unroll
          for (int j = 0; j < 4; ++j)
            G0[j] = *(const unsigned int*)(xbc + cibN[j] + cg * 4);
#pragma unroll
          for (int j = 0; j < 4; ++j)
            G1[j] = *(const unsigned int*)(xbc + cibN[j] + 64 + cg * 4);
        } else {
          const int c0b = ((2 * sp + 2) & 7) * 64 + cg * 4;
#pragma unroll
          for (int j = 0; j < 4; ++j)
            G0[j] = *(const unsigned int*)(xbc + cibC[j] + c0b);
#pragma unroll
          for (int j = 0; j < 4; ++j)
            G1[j] = *(const unsigned int*)(xbc + cibC[j] + c0b + 64);
        }
      }
      MFMA_BODY(PB, B0)
      if (more) {
        const int cn0 = k9 * 8 + 2 * sp + 2;
#pragma unroll
        for (int i = 0; i < 2; ++i)
          B0[i] = wp[(cn0 * 16 + bfo + i) * 64 + lane];
      }
      MFMA_BODY(PB + 4096, B1)
      if (more) {
        const int cn1 = k9 * 8 + 2 * sp + 3;
#pragma unroll
        for (int i = 0; i < 2; ++i)
          B1[i] = wp[(cn1 * 16 + bfo + i) * 64 + lane];
      }
      if (sp == 3 && k9 < 8) {   // advance combine tap params
#pragma unroll
        for (int j = 0; j < 4; ++j) { cwrC[j] = cwrN[j]; cibC[j] = cibN[j]; }
      }
    }
  }
#undef COMBINE_STORE
#undef MFMA_BODY

  if (outf) {
    // final layer: ReLU + direct fp32 NCHW scatter (float4 per tile-row)
#pragma unroll
    for (int mt = 0; mt < 2; ++mt)
#pragma unroll
      for (int nt = 0; nt < 2; ++nt) {
        const int n = wv * 32 + nt * 16 + frow;
        const int pos = h * 64 + w0 + mt * 16 + quad * 4;
        float4 vv;
        vv.x = fmaxf(acc[mt][nt][0], 0.f);
        vv.y = fmaxf(acc[mt][nt][1], 0.f);
        vv.z = fmaxf(acc[mt][nt][2], 0.f);
        vv.w = fmaxf(acc[mt][nt][3], 0.f);
        *(float4*)&outf[(size_t)(b * 256 + n) * HW + pos] = vv;
      }
  } else {
    // layers 0-2: ReLU + bf16-hi transposed plane via per-wave LDS slice
    __syncthreads();   // full drain before smem union reuse
    unsigned short* sW = (unsigned short*)smem + wv * (32 * 36);  // [32][36]
#pragma unroll
    for (int mt = 0; mt < 2; ++mt)
#pragma unroll
      for (int nt = 0; nt < 2; ++nt)
#pragma unroll
        for (int r = 0; r < 4; ++r)
          sW[(mt * 16 + quad * 4 + r) * 36 + nt * 16 + frow] =
              (unsigned short)f2bf_bits(fmaxf(acc[mt][nt][r], 0.f));
    __syncthreads();
    const int lm = lane & 31, cg2 = lane >> 5;
    const int pos = h * 64 + w0 + lm;
    unsigned short* __restrict__ yp =
        yth + ((size_t)b * HW + pos) * 256 + wv * 32 + cg2 * 16;
#pragma unroll
    for (int g = 0; g < 2; ++g)
      *(u16x8*)(yp + g * 8) = *(const u16x8*)&sW[lm * 36 + cg2 * 16 + g * 8];
  }
}

extern "C" void kernel_launch(void* const* d_in, const int* in_sizes, int n_in,
                              void* d_out, int out_size, void* d_ws, size_t ws_size,
                              hipStream_t stream) {
  const float* x0   = (const float*)d_in[0];  // [4][256][64][64]
  const float* offw = (const float*)d_in[1];  // [4][18][256][3][3]
  const float* offb = (const float*)d_in[2];  // [4][18]
  const float* w    = (const float*)d_in[3];  // [4][256][256][3][3]
  float* out = (float*)d_out;                 // [4][256][64][64]
  float* ws  = (float*)d_ws;

  float* offs = ws;                                     //   294,912 floats
  unsigned short* wph  = (unsigned short*)(ws + 294912);    // 2,359,296 ushort
  unsigned short* owph = wph + 2359296;                     //   294,912 ushort
  unsigned short* xTA  = owph + 294912;                     // 4,194,304 ushort
  unsigned short* xTB  = xTA + 4194304;                     // 4,194,304 ushort

  wpack_kernel<<<9216, 256, 0, stream>>>(w, wph);
  offwpack_kernel<<<1152, 256, 0, stream>>>(offw, owph);
  xpose_kernel<<<dim3(64, 4, 4), 256, 0, stream>>>(x0, xTA);

  unsigned short* pin = xTA;
  unsigned short* pout = xTB;
  for (int r = 0; r < 4; ++r) {
    offconv_mfma<<<512, 512, 0, stream>>>(pin, owph + r * 73728,
                                          offb + r * 18, offs);
    deform_mfma<<<512, 512, 0, stream>>>(pin, offs,
                                         wph + (size_t)r * 589824,
                                         (r < 3) ? pout : nullptr,
                                         (r < 3) ? nullptr : out);
    unsigned short* tmp = pin; pin = pout; pout = tmp;
  }
}

// Round 6
// 339.842 us; speedup vs baseline: 1.4676x; 1.0206x over previous
//
#include <hip/hip_runtime.h>

// RepetHead: 4 layers of (3x3 offset conv -> DCNv1 deform conv -> ReLU)
// B=4, C=256, H=W=64, K=9 taps.
// Round 12: offconv FUSED into deform as a block head. Each deform block
// (b,h,w-half) computes its own 18x32 offset tile (M=32,N=32-padded,
// K=2304 = 288 MFMAs/block, +6% MFMA) into LDS, removing the standalone
// offconv dispatch, the offs global round-trip, and -- the real win --
// the chip-wide serial latency phase: the head's load-bound stretch now
// co-schedules against the co-resident block's MFMA-rich main loop.
// Head double-buffers 2-chunk steps (8 x u16x8 = 32 VGPR transient).
// R9-R11 learnings kept: SQ_LDS_BANK_CONFLICT=5.0/ds_read_b128 intrinsic;
// lgkm-only barriers in K-loop; 2-chunk super-bodies; cvt_pk combine.
//
// ws layout (floats):
//   (294,912 floats reserved, unused since R12)
//   wph  : 1,179,648  (2,359,296 ushort, deform B frag-packed, bf16-hi)
//   owph :   147,456  (  294,912 ushort, offset-conv B frag-packed)
//   xTA  : 2,097,152  (4,194,304 ushort, plane ping)
//   xTB  : 2,097,152  (4,194,304 ushort, plane pong)

#define HW 4096

typedef __attribute__((ext_vector_type(8))) __bf16 bf16x8;
typedef __attribute__((ext_vector_type(4))) float f32x4;
typedef __attribute__((ext_vector_type(8))) unsigned short u16x8;

__device__ inline unsigned int f2bf_bits(float f) {
  unsigned int u = __float_as_uint(f);
  return (u + 0x7fffu + ((u >> 16) & 1u)) >> 16;   // RNE to bf16
}

// Workgroup barrier with LDS-only ordering: no vmcnt drain, so global
// prefetches stay in flight across it. sched_barrier pins ds_read motion.
__device__ inline void wg_barrier_lds() {
  asm volatile("s_waitcnt lgkmcnt(0)" ::: "memory");
  __builtin_amdgcn_s_barrier();
  __builtin_amdgcn_sched_barrier(0);
}

// ---------------------------------------------------------------------------
// w[r][o][c][ky][kx] -> frag-packed wph[r][q=72][nt=16][lane=64][j=8] (bf16-hi)
// n = nt*16+(lane&15); kk = q*32+(lane>>4)*8+j; c = kk&255; k = kk>>8.
__global__ __launch_bounds__(256) void wpack_kernel(
    const float* __restrict__ w, unsigned short* __restrict__ wph) {
  const int f = blockIdx.x * 256 + threadIdx.x;   // < 2,359,296
  const int j  = f & 7;
  const int l  = (f >> 3) & 63;
  const int nt = (f >> 9) & 15;
  const int q  = (f >> 13) % 72;
  const int r  = f / 589824;
  const int n  = nt * 16 + (l & 15);
  const int kk = q * 32 + ((l >> 4) << 3) + j;
  const int c  = kk & 255, k = kk >> 8;
  wph[f] = (unsigned short)f2bf_bits(w[((r * 256 + n) * 256 + c) * 9 + k]);
}

// offw[r][18][256][3][3] -> owph[r][q=72][nt=2][lane=64][j=8] (n>=18 -> 0)
__global__ __launch_bounds__(256) void offwpack_kernel(
    const float* __restrict__ offw, unsigned short* __restrict__ owph) {
  const int f = blockIdx.x * 256 + threadIdx.x;   // < 294,912
  const int j  = f & 7;
  const int l  = (f >> 3) & 63;
  const int nt = (f >> 9) & 1;
  const int q  = (f >> 10) % 72;
  const int r  = f / 73728;
  const int n  = nt * 16 + (l & 15);
  const int kk = q * 32 + ((l >> 4) << 3) + j;
  const int c  = kk & 255, k = kk >> 8;
  const float v = (n < 18) ? offw[((r * 18 + n) * 256 + c) * 9 + k] : 0.f;
  owph[f] = (unsigned short)f2bf_bits(v);
}

// ---------------------------------------------------------------------------
// x [4][256][4096] fp32 -> xT [4][4096][256] bf16-hi (transpose + cast)
__global__ __launch_bounds__(256) void xpose_kernel(
    const float* __restrict__ x, unsigned short* __restrict__ xh) {
  const int p0 = blockIdx.x * 64;     // pos tile
  const int c0 = blockIdx.y * 64;     // channel tile
  const int b  = blockIdx.z;
  __shared__ float sT[64][65];
  const int t = threadIdx.x;
  const int pj = t & 63, ci0 = (t >> 6) * 16;
  const float* __restrict__ xb = x + ((size_t)(b * 256 + c0)) * HW + p0;
#pragma unroll
  for (int u = 0; u < 16; ++u)
    sT[ci0 + u][pj] = xb[(size_t)(ci0 + u) * HW + pj];
  __syncthreads();
  const int pr = t >> 2, cs = (t & 3) * 16;
  u16x8 va, vb;
#pragma unroll
  for (int u = 0; u < 8; ++u) va[u] = (unsigned short)f2bf_bits(sT[cs + u][pr]);
#pragma unroll
  for (int u = 0; u < 8; ++u) vb[u] = (unsigned short)f2bf_bits(sT[cs + 8 + u][pr]);
  const size_t o = ((size_t)b * HW + p0 + pr) * 256 + c0 + cs;
  *(u16x8*)(xh + o) = va;
  *(u16x8*)(xh + o + 8) = vb;
}

// ---------------------------------------------------------------------------
// FUSED: offset-conv head + bilinear-sample + bf16 MFMA GEMM + ReLU.
// Block: M=32 (half row), N=256, 512 threads = 8 waves.
// Head: (mtO,ntO,kv)=(wv&1,(wv>>1)&1,wv>>2), K split across kv halves,
// LDS f32x4 reduction, offsets land in s_off[18][32] (LDS).
// Main loop: 2-chunk super-bodies, 4 x 4KB LDS sub-buffers, lgkm-only
// barriers, gather/B prefetch ~1 super ahead, setprio around MFMA.
__global__ __launch_bounds__(512, 4) void deform_mfma(
    const unsigned short* __restrict__ xh,   // [4][4096][256] bf16-hi plane
    const unsigned short* __restrict__ owh,  // offset B frags, this layer
    const float* __restrict__ offb,          // bias[18], this layer
    const unsigned short* __restrict__ wph,  // [72][16][64][8] this layer
    unsigned short* __restrict__ yth,        // next plane (layers 0-2)
    float* __restrict__ outf) {              // fp32 NCHW out (layer 3)
  const int gid = blockIdx.x;                  // 0..511
  const int b = (gid & 7) >> 1;                // 2 XCDs per batch image
  const int idx = ((gid >> 3) << 1) | (gid & 1);   // 0..127
  const int h = idx >> 1, w0 = (idx & 1) << 5;     // half-row of 32
  const int t = threadIdx.x, lane = t & 63, wv = t >> 6;   // 8 waves
  const int frow = lane & 15, quad = lane >> 4;
  const int sm = t >> 4, cg = t & 15;          // staging: row 0..31, pair 0..15

  __shared__ __align__(16) unsigned char smem[25600];
  float* s_cw = (float*)smem;                  // [9][4][32] = 4608 B
  int*   s_ci = (int*)(smem + 4608);           // [9][4][32] = 4608 B
  unsigned char* sAb = smem + 9216;            // 4 sub-bufs x 4096 B
  float* s_off = (float*)(smem + 13312);       // [18][32] (head output)

  // ======== offset-conv head: this block's 18x32 offsets -> s_off ========
  {
    const int kv = wv >> 2, ntO = (wv >> 1) & 1, mtO = wv & 1;
    const int mO = w0 + mtO * 16 + frow;       // w coordinate of A row
    f32x4 aoc = {0.f, 0.f, 0.f, 0.f};
    const u16x8 z8 = {};
    const size_t xb = (size_t)b * HW;
    const u16x8* __restrict__ owp = (const u16x8*)owh;

#define OHLOAD(k, p, A, Bv)                                                 \
  {                                                                         \
    const int ky = (k) / 3 - 1, kx = (k) % 3 - 1;                           \
    const int hy = h + ky;                                                  \
    const int hyc = hy < 0 ? 0 : (hy > 63 ? 63 : hy);                       \
    const int mx = mO + kx;                                                 \
    const bool v = ((unsigned)hy < 64u) && ((unsigned)mx < 64u);            \
    const int cpx = mx < 0 ? 0 : (mx > 63 ? 63 : mx);                       \
    const size_t abase = (xb + (size_t)(hyc * 64 + cpx)) * 256              \
                         + quad * 8 + kv * 128 + (p) * 64;                  \
    _Pragma("unroll") for (int j = 0; j < 2; ++j) {                         \
      A[j] = *(const u16x8*)(xh + abase + j * 32);                          \
      if (!v) A[j] = z8;                                                    \
    }                                                                       \
    _Pragma("unroll") for (int j = 0; j < 2; ++j)                           \
      Bv[j] = owp[(((k) * 8 + kv * 4 + (p) * 2 + j) * 2 + ntO) * 64 + lane];\
  }

#define OHMFMA(A, Bv)                                                       \
  _Pragma("unroll") for (int j = 0; j < 2; ++j)                             \
    aoc = __builtin_amdgcn_mfma_f32_16x16x32_bf16(                          \
        __builtin_bit_cast(bf16x8, A[j]), __builtin_bit_cast(bf16x8, Bv[j]),\
        aoc, 0, 0, 0);

    u16x8 A0[2], Bv0[2], A1[2], Bv1[2];
    OHLOAD(0, 0, A0, Bv0)
    OHLOAD(0, 1, A1, Bv1)
    OHMFMA(A0, Bv0) OHLOAD(1, 0, A0, Bv0)
    OHMFMA(A1, Bv1) OHLOAD(1, 1, A1, Bv1)
    OHMFMA(A0, Bv0) OHLOAD(2, 0, A0, Bv0)
    OHMFMA(A1, Bv1) OHLOAD(2, 1, A1, Bv1)
    OHMFMA(A0, Bv0) OHLOAD(3, 0, A0, Bv0)
    OHMFMA(A1, Bv1) OHLOAD(3, 1, A1, Bv1)
    OHMFMA(A0, Bv0) OHLOAD(4, 0, A0, Bv0)
    OHMFMA(A1, Bv1) OHLOAD(4, 1, A1, Bv1)
    OHMFMA(A0, Bv0) OHLOAD(5, 0, A0, Bv0)
    OHMFMA(A1, Bv1) OHLOAD(5, 1, A1, Bv1)
    OHMFMA(A0, Bv0) OHLOAD(6, 0, A0, Bv0)
    OHMFMA(A1, Bv1) OHLOAD(6, 1, A1, Bv1)
    OHMFMA(A0, Bv0) OHLOAD(7, 0, A0, Bv0)
    OHMFMA(A1, Bv1) OHLOAD(7, 1, A1, Bv1)
    OHMFMA(A0, Bv0) OHLOAD(8, 0, A0, Bv0)
    OHMFMA(A1, Bv1) OHLOAD(8, 1, A1, Bv1)
    OHMFMA(A0, Bv0)
    OHMFMA(A1, Bv1)
#undef OHLOAD
#undef OHMFMA

    f32x4* redp = (f32x4*)(smem + 9216);       // transient, pre-main-loop
    if (kv == 1) redp[(mtO * 2 + ntO) * 64 + lane] = aoc;
    __syncthreads();
    if (kv == 0) {
      const f32x4 o = redp[(mtO * 2 + ntO) * 64 + lane];
      aoc[0] += o[0]; aoc[1] += o[1]; aoc[2] += o[2]; aoc[3] += o[3];
      const int oc = ntO * 16 + frow;          // C/D: col = lane&15 -> n
      if (oc < 18) {
        const float bv = offb[oc];
        const int mb = mtO * 16 + quad * 4;    // C/D row = (lane>>4)*4 + r
#pragma unroll
        for (int r = 0; r < 4; ++r) s_off[oc * 32 + mb + r] = aoc[r] + bv;
      }
    }
    __syncthreads();
  }

  // ======== phase 0: per (k, m) bilinear setup from s_off ========
  for (int i = t; i < 288; i += 512) {
    const int k = i >> 5, m = i & 31;
    const int ky = k / 3 - 1, kx = k % 3 - 1;
    const int mw = w0 + m;
    const float dy = s_off[(2 * k) * 32 + m];
    const float dx = s_off[(2 * k + 1) * 32 + m];
    const float py = (float)(h + ky) + dy;
    const float px = (float)(mw + kx) + dx;
    const float y0f = floorf(py), x0f = floorf(px);
    const float wy = py - y0f, wx = px - x0f;
    const int y0 = (int)y0f, x0 = (int)x0f;
#pragma unroll
    for (int j = 0; j < 4; ++j) {
      const int yi = y0 + (j >> 1), xi = x0 + (j & 1);
      const bool v = (yi >= 0) && (yi < 64) && (xi >= 0) && (xi < 64);
      const float wgt = ((j >> 1) ? wy : 1.f - wy) * ((j & 1) ? wx : 1.f - wx);
      s_cw[(k * 4 + j) * 32 + m] = v ? wgt : 0.f;
      const int yc = yi < 0 ? 0 : (yi > 63 ? 63 : yi);
      const int xc = xi < 0 ? 0 : (xi > 63 ? 63 : xi);
      s_ci[(k * 4 + j) * 32 + m] = yc * 64 + xc;
    }
  }
  __syncthreads();

  f32x4 acc[2][2];
#pragma unroll
  for (int mt = 0; mt < 2; ++mt)
#pragma unroll
    for (int nt = 0; nt < 2; ++nt) acc[mt][nt] = (f32x4){0.f, 0.f, 0.f, 0.f};

  const char* __restrict__ xbc = (const char*)(xh + (size_t)b * HW * 256);
  const u16x8* __restrict__ wp = (const u16x8*)wph;
  const int bfo = wv * 2;                      // wave's n-tile base (0..14)

  // XOR-swizzled staging addresses (loop-invariant, per 4KB sub-buffer).
  const int gs = ((sm & 3) << 1) | ((sm >> 2) & 1);
  const int wbA = sm * 128 + ((((cg >> 2) ^ gs)) << 4) + (cg & 3) * 4;  // hi
  const int wbL = wbA ^ 64;                                            // lo
  const int gr = ((frow & 3) << 1) | ((frow >> 2) & 1);
  const int rb0 = frow * 128 + ((quad ^ gr) << 4);        // mt=0 hi
  const int rb1 = rb0 + 2048;                             // mt=1 hi

  unsigned int G0[4], G1[4];
  u16x8 B0[2], B1[2];
  float cwrC[4], cwrN[4];
  int cibC[4], cibN[4];
#pragma unroll
  for (int j = 0; j < 4; ++j) {   // tap 0 staging params (byte offsets)
    cwrC[j] = s_cw[j * 32 + sm];
    cibC[j] = s_ci[j * 32 + sm] * 512;
  }
#pragma unroll
  for (int j = 0; j < 4; ++j)     // chunk 0 gather
    G0[j] = *(const unsigned int*)(xbc + cibC[j] + cg * 4);
#pragma unroll
  for (int j = 0; j < 4; ++j)     // chunk 1 gather
    G1[j] = *(const unsigned int*)(xbc + cibC[j] + 64 + cg * 4);
#pragma unroll
  for (int i = 0; i < 2; ++i) B0[i] = wp[(bfo + i) * 64 + lane];
#pragma unroll
  for (int i = 0; i < 2; ++i) B1[i] = wp[(16 + bfo + i) * 64 + lane];

#define COMBINE_STORE(Gx, BB)                                               \
  {                                                                         \
    float s0 = cwrC[0] * __uint_as_float(Gx[0] << 16);                      \
    float s1 = cwrC[0] * __uint_as_float(Gx[0] & 0xffff0000u);              \
    s0 = fmaf(cwrC[1], __uint_as_float(Gx[1] << 16), s0);                   \
    s1 = fmaf(cwrC[1], __uint_as_float(Gx[1] & 0xffff0000u), s1);           \
    s0 = fmaf(cwrC[2], __uint_as_float(Gx[2] << 16), s0);                   \
    s1 = fmaf(cwrC[2], __uint_as_float(Gx[2] & 0xffff0000u), s1);           \
    s0 = fmaf(cwrC[3], __uint_as_float(Gx[3] << 16), s0);                   \
    s1 = fmaf(cwrC[3], __uint_as_float(Gx[3] & 0xffff0000u), s1);           \
    const __bf16 hb0 = (__bf16)s0, hb1 = (__bf16)s1;                        \
    const unsigned int hv =                                                 \
        (unsigned int)__builtin_bit_cast(unsigned short, hb0) |             \
        ((unsigned int)__builtin_bit_cast(unsigned short, hb1) << 16);      \
    const float d0 = s0 - __uint_as_float(hv << 16);                        \
    const float d1 = s1 - __uint_as_float(hv & 0xffff0000u);                \
    const __bf16 lb0 = (__bf16)d0, lb1 = (__bf16)d1;                        \
    const unsigned int lv =                                                 \
        (unsigned int)__builtin_bit_cast(unsigned short, lb0) |             \
        ((unsigned int)__builtin_bit_cast(unsigned short, lb1) << 16);      \
    *(unsigned int*)(sAb + (BB) + wbA) = hv;                                \
    *(unsigned int*)(sAb + (BB) + wbL) = lv;                                \
  }

#define MFMA_BODY(BB, Bx)                                                   \
  {                                                                         \
    bf16x8 ah[2], al[2];                                                    \
    ah[0] = __builtin_bit_cast(bf16x8, *(const u16x8*)(sAb + (BB) + rb0));  \
    al[0] = __builtin_bit_cast(bf16x8,                                      \
                               *(const u16x8*)(sAb + (BB) + (rb0 ^ 64)));   \
    ah[1] = __builtin_bit_cast(bf16x8, *(const u16x8*)(sAb + (BB) + rb1));  \
    al[1] = __builtin_bit_cast(bf16x8,                                      \
                               *(const u16x8*)(sAb + (BB) + (rb1 ^ 64)));   \
    __builtin_amdgcn_s_setprio(1);                                          \
    _Pragma("unroll") for (int nt = 0; nt < 2; ++nt) {                      \
      const bf16x8 bv = __builtin_bit_cast(bf16x8, Bx[nt]);                 \
      _Pragma("unroll") for (int mt = 0; mt < 2; ++mt) {                    \
        acc[mt][nt] = __builtin_amdgcn_mfma_f32_16x16x32_bf16(              \
            ah[mt], bv, acc[mt][nt], 0, 0, 0);                              \
        acc[mt][nt] = __builtin_amdgcn_mfma_f32_16x16x32_bf16(              \
            al[mt], bv, acc[mt][nt], 0, 0, 0);                              \
      }                                                                     \
    }                                                                       \
    __builtin_amdgcn_s_setprio(0);                                          \
  }

  for (int k9 = 0; k9 < 9; ++k9) {
#pragma unroll
    for (int sp = 0; sp < 4; ++sp) {           // super = 2 chunks
      const int PB = (sp & 1) * 8192;          // buffer-pair byte base
      // combine chunks (k9*8 + 2*sp, +1) from regs into pair PB
      COMBINE_STORE(G0, PB)
      COMBINE_STORE(G1, PB + 4096)
      wg_barrier_lds();
      const bool more = (k9 < 8) || (sp < 3);
      if (more) {
        if (sp == 3) {         // prefetch crosses into tap k9+1
#pragma unroll
          for (int j = 0; j < 4; ++j) {
            cwrN[j] = s_cw[((k9 + 1) * 4 + j) * 32 + sm];
            cibN[j] = s_ci[((k9 + 1) * 4 + j) * 32 + sm] * 512;
          }
#pragma unroll
          for (int j = 0; j < 4; ++j)
            G0[j] = *(const unsigned int*)(xbc + cibN[j] + cg * 4);
#pragma unroll
          for (int j = 0; j < 4; ++j)
            G1[j] = *(const unsigned int*)(xbc + cibN[j] + 64 + cg * 4);
        } else {
          const int c0b = ((2 * sp + 2) & 7) * 64 + cg * 4;
#pragma unroll
          for (int j = 0; j < 4; ++j)
            G0[j] = *(const unsigned int*)(xbc + cibC[j] + c0b);
#pragma unroll
          for (int j = 0; j < 4; ++j)
            G1[j] = *(const unsigned int*)(xbc + cibC[j] + c0b + 64);
        }
      }
      MFMA_BODY(PB, B0)
      if (more) {
        const int cn0 = k9 * 8 + 2 * sp + 2;
#pragma unroll
        for (int i = 0; i < 2; ++i)
          B0[i] = wp[(cn0 * 16 + bfo + i) * 64 + lane];
      }
      MFMA_BODY(PB + 4096, B1)
      if (more) {
        const int cn1 = k9 * 8 + 2 * sp + 3;
#pragma unroll
        for (int i = 0; i < 2; ++i)
          B1[i] = wp[(cn1 * 16 + bfo + i) * 64 + lane];
      }
      if (sp == 3 && k9 < 8) {   // advance combine tap params
#pragma unroll
        for (int j = 0; j < 4; ++j) { cwrC[j] = cwrN[j]; cibC[j] = cibN[j]; }
      }
    }
  }
#undef COMBINE_STORE
#undef MFMA_BODY

  if (outf) {
    // final layer: ReLU + direct fp32 NCHW scatter (float4 per tile-row)
#pragma unroll
    for (int mt = 0; mt < 2; ++mt)
#pragma unroll
      for (int nt = 0; nt < 2; ++nt) {
        const int n = wv * 32 + nt * 16 + frow;
        const int pos = h * 64 + w0 + mt * 16 + quad * 4;
        float4 vv;
        vv.x = fmaxf(acc[mt][nt][0], 0.f);
        vv.y = fmaxf(acc[mt][nt][1], 0.f);
        vv.z = fmaxf(acc[mt][nt][2], 0.f);
        vv.w = fmaxf(acc[mt][nt][3], 0.f);
        *(float4*)&outf[(size_t)(b * 256 + n) * HW + pos] = vv;
      }
  } else {
    // layers 0-2: ReLU + bf16-hi transposed plane via per-wave LDS slice
    __syncthreads();   // full drain before smem union reuse
    unsigned short* sW = (unsigned short*)smem + wv * (32 * 36);  // [32][36]
#pragma unroll
    for (int mt = 0; mt < 2; ++mt)
#pragma unroll
      for (int nt = 0; nt < 2; ++nt)
#pragma unroll
        for (int r = 0; r < 4; ++r)
          sW[(mt * 16 + quad * 4 + r) * 36 + nt * 16 + frow] =
              (unsigned short)f2bf_bits(fmaxf(acc[mt][nt][r], 0.f));
    __syncthreads();
    const int lm = lane & 31, cg2 = lane >> 5;
    const int pos = h * 64 + w0 + lm;
    unsigned short* __restrict__ yp =
        yth + ((size_t)b * HW + pos) * 256 + wv * 32 + cg2 * 16;
#pragma unroll
    for (int g = 0; g < 2; ++g)
      *(u16x8*)(yp + g * 8) = *(const u16x8*)&sW[lm * 36 + cg2 * 16 + g * 8];
  }
}

extern "C" void kernel_launch(void* const* d_in, const int* in_sizes, int n_in,
                              void* d_out, int out_size, void* d_ws, size_t ws_size,
                              hipStream_t stream) {
  const float* x0   = (const float*)d_in[0];  // [4][256][64][64]
  const float* offw = (const float*)d_in[1];  // [4][18][256][3][3]
  const float* offb = (const float*)d_in[2];  // [4][18]
  const float* w    = (const float*)d_in[3];  // [4][256][256][3][3]
  float* out = (float*)d_out;                 // [4][256][64][64]
  float* ws  = (float*)d_ws;

  unsigned short* wph  = (unsigned short*)(ws + 294912);    // 2,359,296 ushort
  unsigned short* owph = wph + 2359296;                     //   294,912 ushort
  unsigned short* xTA  = owph + 294912;                     // 4,194,304 ushort
  unsigned short* xTB  = xTA + 4194304;                     // 4,194,304 ushort

  wpack_kernel<<<9216, 256, 0, stream>>>(w, wph);
  offwpack_kernel<<<1152, 256, 0, stream>>>(offw, owph);
  xpose_kernel<<<dim3(64, 4, 4), 256, 0, stream>>>(x0, xTA);

  unsigned short* pin = xTA;
  unsigned short* pout = xTB;
  for (int r = 0; r < 4; ++r) {
    deform_mfma<<<512, 512, 0, stream>>>(pin, owph + r * 73728,
                                         offb + r * 18,
                                         wph + (size_t)r * 589824,
                                         (r < 3) ? pout : nullptr,
                                         (r < 3) ? nullptr : out);
    unsigned short* tmp = pin; pin = pout; pout = tmp;
  }
}

// Round 7
// 337.566 us; speedup vs baseline: 1.4775x; 1.0067x over previous
//
#include <hip/hip_runtime.h>

// RepetHead: 4 layers of (3x3 offset conv -> DCNv1 deform conv -> ReLU)
// B=4, C=256, H=W=64, K=9 taps.
// Round 13: deform block M=32 -> M=64 (full row) x N=256, 1024 threads
// (16 waves), grid 256 = 1 block/CU (4 waves/SIMD, same as R12).
// Rationale: kernel is L2-bandwidth-bound (~19 TB/s observed, no pipe
// saturated). Total B-read = (16384/M_block) x 1.18 MB depends ONLY on
// M_block: M=64 halves main-B (604->302 MB/layer) and head-B
// (295->147 MB/layer) L2 traffic at identical per-thread work.
// All R9-R12 machinery kept: XOR-swizzled staging, 2-chunk super-bodies,
// lgkm-only barriers, fused offconv head, cvt_pk combine.
//
// ws layout (floats):
//   (294,912 floats reserved, unused since R12)
//   wph  : 1,179,648  (2,359,296 ushort, deform B frag-packed, bf16-hi)
//   owph :   147,456  (  294,912 ushort, offset-conv B frag-packed)
//   xTA  : 2,097,152  (4,194,304 ushort, plane ping)
//   xTB  : 2,097,152  (4,194,304 ushort, plane pong)

#define HW 4096

typedef __attribute__((ext_vector_type(8))) __bf16 bf16x8;
typedef __attribute__((ext_vector_type(4))) float f32x4;
typedef __attribute__((ext_vector_type(8))) unsigned short u16x8;

__device__ inline unsigned int f2bf_bits(float f) {
  unsigned int u = __float_as_uint(f);
  return (u + 0x7fffu + ((u >> 16) & 1u)) >> 16;   // RNE to bf16
}

// Workgroup barrier with LDS-only ordering: no vmcnt drain, so global
// prefetches stay in flight across it. sched_barrier pins ds_read motion.
__device__ inline void wg_barrier_lds() {
  asm volatile("s_waitcnt lgkmcnt(0)" ::: "memory");
  __builtin_amdgcn_s_barrier();
  __builtin_amdgcn_sched_barrier(0);
}

// ---------------------------------------------------------------------------
// w[r][o][c][ky][kx] -> frag-packed wph[r][q=72][nt=16][lane=64][j=8] (bf16-hi)
// n = nt*16+(lane&15); kk = q*32+(lane>>4)*8+j; c = kk&255; k = kk>>8.
__global__ __launch_bounds__(256) void wpack_kernel(
    const float* __restrict__ w, unsigned short* __restrict__ wph) {
  const int f = blockIdx.x * 256 + threadIdx.x;   // < 2,359,296
  const int j  = f & 7;
  const int l  = (f >> 3) & 63;
  const int nt = (f >> 9) & 15;
  const int q  = (f >> 13) % 72;
  const int r  = f / 589824;
  const int n  = nt * 16 + (l & 15);
  const int kk = q * 32 + ((l >> 4) << 3) + j;
  const int c  = kk & 255, k = kk >> 8;
  wph[f] = (unsigned short)f2bf_bits(w[((r * 256 + n) * 256 + c) * 9 + k]);
}

// offw[r][18][256][3][3] -> owph[r][q=72][nt=2][lane=64][j=8] (n>=18 -> 0)
__global__ __launch_bounds__(256) void offwpack_kernel(
    const float* __restrict__ offw, unsigned short* __restrict__ owph) {
  const int f = blockIdx.x * 256 + threadIdx.x;   // < 294,912
  const int j  = f & 7;
  const int l  = (f >> 3) & 63;
  const int nt = (f >> 9) & 1;
  const int q  = (f >> 10) % 72;
  const int r  = f / 73728;
  const int n  = nt * 16 + (l & 15);
  const int kk = q * 32 + ((l >> 4) << 3) + j;
  const int c  = kk & 255, k = kk >> 8;
  const float v = (n < 18) ? offw[((r * 18 + n) * 256 + c) * 9 + k] : 0.f;
  owph[f] = (unsigned short)f2bf_bits(v);
}

// ---------------------------------------------------------------------------
// x [4][256][4096] fp32 -> xT [4][4096][256] bf16-hi (transpose + cast)
__global__ __launch_bounds__(256) void xpose_kernel(
    const float* __restrict__ x, unsigned short* __restrict__ xh) {
  const int p0 = blockIdx.x * 64;     // pos tile
  const int c0 = blockIdx.y * 64;     // channel tile
  const int b  = blockIdx.z;
  __shared__ float sT[64][65];
  const int t = threadIdx.x;
  const int pj = t & 63, ci0 = (t >> 6) * 16;
  const float* __restrict__ xb = x + ((size_t)(b * 256 + c0)) * HW + p0;
#pragma unroll
  for (int u = 0; u < 16; ++u)
    sT[ci0 + u][pj] = xb[(size_t)(ci0 + u) * HW + pj];
  __syncthreads();
  const int pr = t >> 2, cs = (t & 3) * 16;
  u16x8 va, vb;
#pragma unroll
  for (int u = 0; u < 8; ++u) va[u] = (unsigned short)f2bf_bits(sT[cs + u][pr]);
#pragma unroll
  for (int u = 0; u < 8; ++u) vb[u] = (unsigned short)f2bf_bits(sT[cs + 8 + u][pr]);
  const size_t o = ((size_t)b * HW + p0 + pr) * 256 + c0 + cs;
  *(u16x8*)(xh + o) = va;
  *(u16x8*)(xh + o + 8) = vb;
}

// ---------------------------------------------------------------------------
// FUSED: offset-conv head + bilinear-sample + bf16 MFMA GEMM + ReLU.
// Block: M=64 (full row h), N=256, 1024 threads = 16 waves, grid 256
// (1 block/CU). Head: (mtO,ntO,kv)=(wv&3,(wv>>2)&1,wv>>3), K split
// across kv halves, LDS f32x4 reduction, offsets -> s_off[18][64].
// Main loop: wave = m-half (wv&1) x n-group (wv>>1); 2-chunk super-bodies,
// 4 x 8KB LDS sub-buffers, lgkm-only barriers, prefetch ~1 super ahead.
__global__ __launch_bounds__(1024, 4) void deform_mfma(
    const unsigned short* __restrict__ xh,   // [4][4096][256] bf16-hi plane
    const unsigned short* __restrict__ owh,  // offset B frags, this layer
    const float* __restrict__ offb,          // bias[18], this layer
    const unsigned short* __restrict__ wph,  // [72][16][64][8] this layer
    unsigned short* __restrict__ yth,        // next plane (layers 0-2)
    float* __restrict__ outf) {              // fp32 NCHW out (layer 3)
  const int gid = blockIdx.x;                  // 0..255
  const int b = (gid & 7) >> 1;                // 2 XCDs per batch image
  const int h = ((gid >> 3) << 1) | (gid & 1);     // full row 0..63
  const int t = threadIdx.x, lane = t & 63, wv = t >> 6;   // 16 waves
  const int frow = lane & 15, quad = lane >> 4;
  const int sm = t >> 4, cg = t & 15;          // staging: row 0..63, pair 0..15

  __shared__ __align__(16) unsigned char smem[55808];
  float* s_cw = (float*)smem;                  // [9][4][64] = 9216 B
  int*   s_ci = (int*)(smem + 9216);           // [9][4][64] = 9216 B
  unsigned char* sAb = smem + 18432;           // 4 sub-bufs x 8192 B
  float* s_off = (float*)(smem + 51200);       // [18][64] = 4608 B

  // ======== offset-conv head: this block's 18x64 offsets -> s_off ========
  {
    const int kv = wv >> 3, ntO = (wv >> 2) & 1, mtO = wv & 3;
    const int mO = mtO * 16 + frow;            // w coordinate of A row
    f32x4 aoc = {0.f, 0.f, 0.f, 0.f};
    const u16x8 z8 = {};
    const size_t xb = (size_t)b * HW;
    const u16x8* __restrict__ owp = (const u16x8*)owh;

#define OHLOAD(k, p, A, Bv)                                                 \
  {                                                                         \
    const int ky = (k) / 3 - 1, kx = (k) % 3 - 1;                           \
    const int hy = h + ky;                                                  \
    const int hyc = hy < 0 ? 0 : (hy > 63 ? 63 : hy);                       \
    const int mx = mO + kx;                                                 \
    const bool v = ((unsigned)hy < 64u) && ((unsigned)mx < 64u);            \
    const int cpx = mx < 0 ? 0 : (mx > 63 ? 63 : mx);                       \
    const size_t abase = (xb + (size_t)(hyc * 64 + cpx)) * 256              \
                         + quad * 8 + kv * 128 + (p) * 64;                  \
    _Pragma("unroll") for (int j = 0; j < 2; ++j) {                         \
      A[j] = *(const u16x8*)(xh + abase + j * 32);                          \
      if (!v) A[j] = z8;                                                    \
    }                                                                       \
    _Pragma("unroll") for (int j = 0; j < 2; ++j)                           \
      Bv[j] = owp[(((k) * 8 + kv * 4 + (p) * 2 + j) * 2 + ntO) * 64 + lane];\
  }

#define OHMFMA(A, Bv)                                                       \
  _Pragma("unroll") for (int j = 0; j < 2; ++j)                             \
    aoc = __builtin_amdgcn_mfma_f32_16x16x32_bf16(                          \
        __builtin_bit_cast(bf16x8, A[j]), __builtin_bit_cast(bf16x8, Bv[j]),\
        aoc, 0, 0, 0);

    u16x8 A0[2], Bv0[2], A1[2], Bv1[2];
    OHLOAD(0, 0, A0, Bv0)
    OHLOAD(0, 1, A1, Bv1)
    OHMFMA(A0, Bv0) OHLOAD(1, 0, A0, Bv0)
    OHMFMA(A1, Bv1) OHLOAD(1, 1, A1, Bv1)
    OHMFMA(A0, Bv0) OHLOAD(2, 0, A0, Bv0)
    OHMFMA(A1, Bv1) OHLOAD(2, 1, A1, Bv1)
    OHMFMA(A0, Bv0) OHLOAD(3, 0, A0, Bv0)
    OHMFMA(A1, Bv1) OHLOAD(3, 1, A1, Bv1)
    OHMFMA(A0, Bv0) OHLOAD(4, 0, A0, Bv0)
    OHMFMA(A1, Bv1) OHLOAD(4, 1, A1, Bv1)
    OHMFMA(A0, Bv0) OHLOAD(5, 0, A0, Bv0)
    OHMFMA(A1, Bv1) OHLOAD(5, 1, A1, Bv1)
    OHMFMA(A0, Bv0) OHLOAD(6, 0, A0, Bv0)
    OHMFMA(A1, Bv1) OHLOAD(6, 1, A1, Bv1)
    OHMFMA(A0, Bv0) OHLOAD(7, 0, A0, Bv0)
    OHMFMA(A1, Bv1) OHLOAD(7, 1, A1, Bv1)
    OHMFMA(A0, Bv0) OHLOAD(8, 0, A0, Bv0)
    OHMFMA(A1, Bv1) OHLOAD(8, 1, A1, Bv1)
    OHMFMA(A0, Bv0)
    OHMFMA(A1, Bv1)
#undef OHLOAD
#undef OHMFMA

    f32x4* redp = (f32x4*)(smem + 18432);      // transient, pre-main-loop
    if (kv == 1) redp[(mtO * 2 + ntO) * 64 + lane] = aoc;
    __syncthreads();
    if (kv == 0) {
      const f32x4 o = redp[(mtO * 2 + ntO) * 64 + lane];
      aoc[0] += o[0]; aoc[1] += o[1]; aoc[2] += o[2]; aoc[3] += o[3];
      const int oc = ntO * 16 + frow;          // C/D: col = lane&15 -> n
      if (oc < 18) {
        const float bv = offb[oc];
        const int mb = mtO * 16 + quad * 4;    // C/D row = (lane>>4)*4 + r
#pragma unroll
        for (int r = 0; r < 4; ++r) s_off[oc * 64 + mb + r] = aoc[r] + bv;
      }
    }
    __syncthreads();
  }

  // ======== phase 0: per (k, m) bilinear setup from s_off ========
  if (t < 576) {
    const int k = t >> 6, m = t & 63;
    const int ky = k / 3 - 1, kx = k % 3 - 1;
    const float dy = s_off[(2 * k) * 64 + m];
    const float dx = s_off[(2 * k + 1) * 64 + m];
    const float py = (float)(h + ky) + dy;
    const float px = (float)(m + kx) + dx;
    const float y0f = floorf(py), x0f = floorf(px);
    const float wy = py - y0f, wx = px - x0f;
    const int y0 = (int)y0f, x0 = (int)x0f;
#pragma unroll
    for (int j = 0; j < 4; ++j) {
      const int yi = y0 + (j >> 1), xi = x0 + (j & 1);
      const bool v = (yi >= 0) && (yi < 64) && (xi >= 0) && (xi < 64);
      const float wgt = ((j >> 1) ? wy : 1.f - wy) * ((j & 1) ? wx : 1.f - wx);
      s_cw[(k * 4 + j) * 64 + m] = v ? wgt : 0.f;
      const int yc = yi < 0 ? 0 : (yi > 63 ? 63 : yi);
      const int xc = xi < 0 ? 0 : (xi > 63 ? 63 : xi);
      s_ci[(k * 4 + j) * 64 + m] = yc * 64 + xc;
    }
  }
  __syncthreads();

  f32x4 acc[2][2];
#pragma unroll
  for (int mt = 0; mt < 2; ++mt)
#pragma unroll
    for (int nt = 0; nt < 2; ++nt) acc[mt][nt] = (f32x4){0.f, 0.f, 0.f, 0.f};

  const char* __restrict__ xbc = (const char*)(xh + (size_t)b * HW * 256);
  const u16x8* __restrict__ wp = (const u16x8*)wph;
  const int bfo = (wv >> 1) * 2;               // wave's n-tile base (0..14)
  const int mb0 = (wv & 1) << 5;               // wave's m-half base

  // XOR-swizzled staging addresses (loop-invariant, per 8KB sub-buffer).
  const int gs = ((sm & 3) << 1) | ((sm >> 2) & 1);
  const int wbA = sm * 128 + ((((cg >> 2) ^ gs)) << 4) + (cg & 3) * 4;  // hi
  const int wbL = wbA ^ 64;                                            // lo
  const int gr = ((frow & 3) << 1) | ((frow >> 2) & 1);
  const int rb0 = (mb0 + frow) * 128 + ((quad ^ gr) << 4);  // mt=0 hi
  const int rb1 = rb0 + 2048;                               // mt=1 hi

  unsigned int G0[4], G1[4];
  u16x8 B0[2], B1[2];
  float cwrC[4], cwrN[4];
  int cibC[4], cibN[4];
#pragma unroll
  for (int j = 0; j < 4; ++j) {   // tap 0 staging params (byte offsets)
    cwrC[j] = s_cw[j * 64 + sm];
    cibC[j] = s_ci[j * 64 + sm] * 512;
  }
#pragma unroll
  for (int j = 0; j < 4; ++j)     // chunk 0 gather
    G0[j] = *(const unsigned int*)(xbc + cibC[j] + cg * 4);
#pragma unroll
  for (int j = 0; j < 4; ++j)     // chunk 1 gather
    G1[j] = *(const unsigned int*)(xbc + cibC[j] + 64 + cg * 4);
#pragma unroll
  for (int i = 0; i < 2; ++i) B0[i] = wp[(bfo + i) * 64 + lane];
#pragma unroll
  for (int i = 0; i < 2; ++i) B1[i] = wp[(16 + bfo + i) * 64 + lane];

#define COMBINE_STORE(Gx, BB)                                               \
  {                                                                         \
    float s0 = cwrC[0] * __uint_as_float(Gx[0] << 16);                      \
    float s1 = cwrC[0] * __uint_as_float(Gx[0] & 0xffff0000u);              \
    s0 = fmaf(cwrC[1], __uint_as_float(Gx[1] << 16), s0);                   \
    s1 = fmaf(cwrC[1], __uint_as_float(Gx[1] & 0xffff0000u), s1);           \
    s0 = fmaf(cwrC[2], __uint_as_float(Gx[2] << 16), s0);                   \
    s1 = fmaf(cwrC[2], __uint_as_float(Gx[2] & 0xffff0000u), s1);           \
    s0 = fmaf(cwrC[3], __uint_as_float(Gx[3] << 16), s0);                   \
    s1 = fmaf(cwrC[3], __uint_as_float(Gx[3] & 0xffff0000u), s1);           \
    const __bf16 hb0 = (__bf16)s0, hb1 = (__bf16)s1;                        \
    const unsigned int hv =                                                 \
        (unsigned int)__builtin_bit_cast(unsigned short, hb0) |             \
        ((unsigned int)__builtin_bit_cast(unsigned short, hb1) << 16);      \
    const float d0 = s0 - __uint_as_float(hv << 16);                        \
    const float d1 = s1 - __uint_as_float(hv & 0xffff0000u);                \
    const __bf16 lb0 = (__bf16)d0, lb1 = (__bf16)d1;                        \
    const unsigned int lv =                                                 \
        (unsigned int)__builtin_bit_cast(unsigned short, lb0) |             \
        ((unsigned int)__builtin_bit_cast(unsigned short, lb1) << 16);      \
    *(unsigned int*)(sAb + (BB) + wbA) = hv;                                \
    *(unsigned int*)(sAb + (BB) + wbL) = lv;                                \
  }

#define MFMA_BODY(BB, Bx)                                                   \
  {                                                                         \
    bf16x8 ah[2], al[2];                                                    \
    ah[0] = __builtin_bit_cast(bf16x8, *(const u16x8*)(sAb + (BB) + rb0));  \
    al[0] = __builtin_bit_cast(bf16x8,                                      \
                               *(const u16x8*)(sAb + (BB) + (rb0 ^ 64)));   \
    ah[1] = __builtin_bit_cast(bf16x8, *(const u16x8*)(sAb + (BB) + rb1));  \
    al[1] = __builtin_bit_cast(bf16x8,                                      \
                               *(const u16x8*)(sAb + (BB) + (rb1 ^ 64)));   \
    __builtin_amdgcn_s_setprio(1);                                          \
    _Pragma("unroll") for (int nt = 0; nt < 2; ++nt) {                      \
      const bf16x8 bv = __builtin_bit_cast(bf16x8, Bx[nt]);                 \
      _Pragma("unroll") for (int mt = 0; mt < 2; ++mt) {                    \
        acc[mt][nt] = __builtin_amdgcn_mfma_f32_16x16x32_bf16(              \
            ah[mt], bv, acc[mt][nt], 0, 0, 0);                              \
        acc[mt][nt] = __builtin_amdgcn_mfma_f32_16x16x32_bf16(              \
            al[mt], bv, acc[mt][nt], 0, 0, 0);                              \
      }                                                                     \
    }                                                                       \
    __builtin_amdgcn_s_setprio(0);                                          \
  }

  for (int k9 = 0; k9 < 9; ++k9) {
#pragma unroll
    for (int sp = 0; sp < 4; ++sp) {           // super = 2 chunks
      const int PB = (sp & 1) * 16384;         // buffer-pair byte base
      // combine chunks (k9*8 + 2*sp, +1) from regs into pair PB
      COMBINE_STORE(G0, PB)
      COMBINE_STORE(G1, PB + 8192)
      wg_barrier_lds();
      const bool more = (k9 < 8) || (sp < 3);
      if (more) {
        if (sp == 3) {         // prefetch crosses into tap k9+1
#pragma unroll
          for (int j = 0; j < 4; ++j) {
            cwrN[j] = s_cw[((k9 + 1) * 4 + j) * 64 + sm];
            cibN[j] = s_ci[((k9 + 1) * 4 + j) * 64 + sm] * 512;
          }
#pragma unroll
          for (int j = 0; j < 4; ++j)
            G0[j] = *(const unsigned int*)(xbc + cibN[j] + cg * 4);
#pragma unroll
          for (int j = 0; j < 4; ++j)
            G1[j] = *(const unsigned int*)(xbc + cibN[j] + 64 + cg * 4);
        } else {
          const int c0b = ((2 * sp + 2) & 7) * 64 + cg * 4;
#pragma unroll
          for (int j = 0; j < 4; ++j)
            G0[j] = *(const unsigned int*)(xbc + cibC[j] + c0b);
#pragma unroll
          for (int j = 0; j < 4; ++j)
            G1[j] = *(const unsigned int*)(xbc + cibC[j] + c0b + 64);
        }
      }
      MFMA_BODY(PB, B0)
      if (more) {
        const int cn0 = k9 * 8 + 2 * sp + 2;
#pragma unroll
        for (int i = 0; i < 2; ++i)
          B0[i] = wp[(cn0 * 16 + bfo + i) * 64 + lane];
      }
      MFMA_BODY(PB + 8192, B1)
      if (more) {
        const int cn1 = k9 * 8 + 2 * sp + 3;
#pragma unroll
        for (int i = 0; i < 2; ++i)
          B1[i] = wp[(cn1 * 16 + bfo + i) * 64 + lane];
      }
      if (sp == 3 && k9 < 8) {   // advance combine tap params
#pragma unroll
        for (int j = 0; j < 4; ++j) { cwrC[j] = cwrN[j]; cibC[j] = cibN[j]; }
      }
    }
  }
#undef COMBINE_STORE
#undef MFMA_BODY

  if (outf) {
    // final layer: ReLU + direct fp32 NCHW scatter (float4 per tile-row)
#pragma unroll
    for (int mt = 0; mt < 2; ++mt)
#pragma unroll
      for (int nt = 0; nt < 2; ++nt) {
        const int n = (wv >> 1) * 32 + nt * 16 + frow;
        const int pos = h * 64 + mb0 + mt * 16 + quad * 4;
        float4 vv;
        vv.x = fmaxf(acc[mt][nt][0], 0.f);
        vv.y = fmaxf(acc[mt][nt][1], 0.f);
        vv.z = fmaxf(acc[mt][nt][2], 0.f);
        vv.w = fmaxf(acc[mt][nt][3], 0.f);
        *(float4*)&outf[(size_t)(b * 256 + n) * HW + pos] = vv;
      }
  } else {
    // layers 0-2: ReLU + bf16-hi transposed plane via per-wave LDS slice
    __syncthreads();   // full drain before smem union reuse
    unsigned short* sW = (unsigned short*)smem + wv * (32 * 36);  // [32][36]
#pragma unroll
    for (int mt = 0; mt < 2; ++mt)
#pragma unroll
      for (int nt = 0; nt < 2; ++nt)
#pragma unroll
        for (int r = 0; r < 4; ++r)
          sW[(mt * 16 + quad * 4 + r) * 36 + nt * 16 + frow] =
              (unsigned short)f2bf_bits(fmaxf(acc[mt][nt][r], 0.f));
    __syncthreads();
    const int lm = lane & 31, cg2 = lane >> 5;
    const int pos = h * 64 + mb0 + lm;
    unsigned short* __restrict__ yp =
        yth + ((size_t)b * HW + pos) * 256 + (wv >> 1) * 32 + cg2 * 16;
#pragma unroll
    for (int g = 0; g < 2; ++g)
      *(u16x8*)(yp + g * 8) = *(const u16x8*)&sW[lm * 36 + cg2 * 16 + g * 8];
  }
}

extern "C" void kernel_launch(void* const* d_in, const int* in_sizes, int n_in,
                              void* d_out, int out_size, void* d_ws, size_t ws_size,
                              hipStream_t stream) {
  const float* x0   = (const float*)d_in[0];  // [4][256][64][64]
  const float* offw = (const float*)d_in[1];  // [4][18][256][3][3]
  const float* offb = (const float*)d_in[2];  // [4][18]
  const float* w    = (const float*)d_in[3];  // [4][256][256][3][3]
  float* out = (float*)d_out;                 // [4][256][64][64]
  float* ws  = (float*)d_ws;

  unsigned short* wph  = (unsigned short*)(ws + 294912);    // 2,359,296 ushort
  unsigned short* owph = wph + 2359296;                     //   294,912 ushort
  unsigned short* xTA  = owph + 294912;                     // 4,194,304 ushort
  unsigned short* xTB  = xTA + 4194304;                     // 4,194,304 ushort

  wpack_kernel<<<9216, 256, 0, stream>>>(w, wph);
  offwpack_kernel<<<1152, 256, 0, stream>>>(offw, owph);
  xpose_kernel<<<dim3(64, 4, 4), 256, 0, stream>>>(x0, xTA);

  unsigned short* pin = xTA;
  unsigned short* pout = xTB;
  for (int r = 0; r < 4; ++r) {
    deform_mfma<<<256, 1024, 0, stream>>>(pin, owph + r * 73728,
                                          offb + r * 18,
                                          wph + (size_t)r * 589824,
                                          (r < 3) ? pout : nullptr,
                                          (r < 3) ? nullptr : out);
    unsigned short* tmp = pin; pin = pout; pout = tmp;
  }
}